// Round 2
// baseline (701.913 us; speedup 1.0000x reference)
//
#include <hip/hip_runtime.h>
#include <stdint.h>
#include <math.h>

typedef unsigned short u16;
typedef short bf16x8 __attribute__((ext_vector_type(8)));
typedef float f32x4 __attribute__((ext_vector_type(4)));

#define MFMA16x16x32(a,b,c) __builtin_amdgcn_mfma_f32_16x16x32_bf16((a),(b),(c),0,0,0)

typedef __attribute__((address_space(3))) void as3_void;
typedef const __attribute__((address_space(1))) void as1_void;

__device__ __forceinline__ void g2l16(const void* g, void* l){
#if __has_builtin(__builtin_amdgcn_global_load_lds)
  __builtin_amdgcn_global_load_lds((as1_void*)g, (as3_void*)l, 16, 0, 0);
#else
  *(int4*)l = *(const int4*)g;
#endif
}

__device__ __forceinline__ u16 f2bf(float f){
  uint32_t u = __builtin_bit_cast(uint32_t, f);
  u += 0x7fffu + ((u >> 16) & 1u);
  return (u16)(u >> 16);
}
__device__ __forceinline__ float bf2f(u16 h){
  uint32_t u = ((uint32_t)h) << 16;
  return __builtin_bit_cast(float, u);
}
__device__ __forceinline__ void unpack8(int4 v, float* o){
  uint32_t w0=(uint32_t)v.x, w1=(uint32_t)v.y, w2=(uint32_t)v.z, w3=(uint32_t)v.w;
  o[0]=__builtin_bit_cast(float, w0<<16); o[1]=__builtin_bit_cast(float, w0&0xffff0000u);
  o[2]=__builtin_bit_cast(float, w1<<16); o[3]=__builtin_bit_cast(float, w1&0xffff0000u);
  o[4]=__builtin_bit_cast(float, w2<<16); o[5]=__builtin_bit_cast(float, w2&0xffff0000u);
  o[6]=__builtin_bit_cast(float, w3<<16); o[7]=__builtin_bit_cast(float, w3&0xffff0000u);
}
__device__ __forceinline__ int iclampi(int v,int lo,int hi){ return v<lo?lo:(v>hi?hi:v); }

// ---------------------------------------------------------------------------
// Weights frag-packed per K-tile-64 chunk (slot decode identical to round 1;
// only the thread->slot staging assignment in the conv changed).
__global__ void k_repack(const float* __restrict__ w_reset, const float* __restrict__ b_reset,
                         const float* __restrict__ w_update, const float* __restrict__ b_update,
                         const float* __restrict__ w_out, const float* __restrict__ w_offset,
                         const float* __restrict__ w_align,
                         u16* __restrict__ wgate, u16* __restrict__ wout,
                         u16* __restrict__ walign, float* __restrict__ woff,
                         float* __restrict__ biascat){
  int idx = blockIdx.x * 256 + threadIdx.x;
  if (idx < 512*4608){           // gate: BN=256, nb in {0,1}
    int e = idx & 7, j = (idx >> 3) & 2047, chunk = idx >> 14;
    int nb = chunk & 1, kk = chunk >> 1;
    int l = j & 15, q = (j >> 4) & 3, t16 = (j >> 6) & 15, ks2 = j >> 10;
    int n = nb*256 + t16*16 + l;
    int tap = kk >> 3, ksin = kk & 7;
    int c = ksin*64 + ks2*32 + q*8 + e;
    int ky = tap/3, kx = tap%3;
    float v = (n < 256) ? w_update[((n*512 + c)*3 + ky)*3 + kx]
                        : w_reset[(((n-256)*512 + c)*3 + ky)*3 + kx];
    wgate[idx] = f2bf(v);
  }
  if (idx < 256*4608){           // out: BN=128, nb in {0,1}
    int e = idx & 7, j = (idx >> 3) & 1023, chunk = idx >> 13;
    int nb = chunk & 1, kk = chunk >> 1;
    int l = j & 15, q = (j >> 4) & 3, t8 = (j >> 6) & 7, ks2 = j >> 9;
    int n = nb*128 + t8*16 + l;
    int tap = kk >> 3, ksin = kk & 7;
    int c = ksin*64 + ks2*32 + q*8 + e;
    int ky = tap/3, kx = tap%3;
    wout[idx] = f2bf(w_out[((n*512 + c)*3 + ky)*3 + kx]);
  }
  if (idx < 256*2304){           // align (k_deform reads directly)
    int n = idx / 2304, k = idx % 2304;
    int tap = k >> 8, c = k & 255;
    int ky = tap/3, kx = tap%3;
    walign[idx] = f2bf(w_align[((n*256 + c)*3 + ky)*3 + kx]);
  }
  if (idx < 1458) woff[idx] = w_offset[idx] * (1.f/256.f);
  if (idx < 512) biascat[idx] = (idx < 256) ? b_update[idx] : b_reset[idx-256];
}

// ---------------------------------------------------------------------------
// NCHW fp32 -> NHWC bf16.
__global__ __launch_bounds__(256) void k_transform(const float* __restrict__ inputs,
    const float* __restrict__ in_state, u16* __restrict__ stacked,
    u16* __restrict__ stacked2, u16* __restrict__ x2pad){
  __shared__ u16 t1[64*264];
  __shared__ u16 t2[64*264];
  int tid = threadIdx.x, bh = blockIdx.x;
  int b = bh >> 6, h = bh & 63;
  int w = tid & 63, cq = tid >> 6;
  for (int i = 0; i < 64; ++i){
    int c = i*4 + cq;
    int gi = ((b*256 + c)*64 + h)*64 + w;
    t1[w*264 + c] = f2bf(inputs[gi]);
    t2[w*264 + c] = f2bf(in_state[gi]);
  }
  __syncthreads();
  int px = tid >> 2, cg = tid & 3;
#pragma unroll
  for (int u = 0; u < 8; ++u){
    int c = cg*64 + u*8;
    int4 v1 = *(const int4*)(t1 + px*264 + c);
    int4 v2 = *(const int4*)(t2 + px*264 + c);
    *(int4*)(stacked  + (((b*66 + h+1)*66) + (px+1))*512 + c) = v1;
    *(int4*)(stacked2 + (((b*66 + h+1)*66) + (px+1))*512 + c) = v1;
    *(int4*)(x2pad    + (((b*72 + h+4)*72) + (px+4))*256 + c) = v2;
  }
}

// ---------------------------------------------------------------------------
// Correlation as masked local GEMM.
__global__ __launch_bounds__(256) void k_corr(const u16* __restrict__ stacked,
    const u16* __restrict__ x2pad, float* __restrict__ corr){
  __shared__ u16 lA[8192];
  __shared__ u16 lB[32768];
  int tid = threadIdx.x, idx = blockIdx.x;
  int b = idx >> 6, ty = (idx >> 3) & 7, tx = idx & 7;
  int h0 = ty*8, w0 = tx*8;
  int wave = tid >> 6, lane = tid & 63, l15 = lane & 15, quad = lane >> 4;
  f32x4 acc[4][4];
#pragma unroll
  for (int i=0;i<4;i++)
#pragma unroll
    for (int j=0;j<4;j++){ f32x4 z = {0.f,0.f,0.f,0.f}; acc[i][j] = z; }

  for (int s = 0; s < 2; ++s){
#pragma unroll
    for (int i = 0; i < 4; ++i){
      int j = tid + i*256;
      int ml = j & 15, q = (j>>4)&3, mt = (j>>6)&3, ks = j >> 8;
      int px = mt*16 + ml, py = px >> 3, pxx = px & 7;
      const u16* g = stacked + (((b*66 + h0+py+1)*66) + (w0+pxx+1))*512 + s*128 + ks*32 + q*8;
      g2l16(g, lA + j*8);
    }
#pragma unroll
    for (int i = 0; i < 16; ++i){
      int j = tid + i*256;
      int nl = j & 15, q = (j>>4)&3, nt = (j>>6)&15, ks = j >> 10;
      int qp = nt*16 + nl, qy = qp >> 4, qx = qp & 15;
      const u16* g = x2pad + (((b*72 + h0+qy)*72) + (w0+qx))*256 + s*128 + ks*32 + q*8;
      g2l16(g, lB + j*8);
    }
    __syncthreads();
#pragma unroll
    for (int ks = 0; ks < 4; ++ks){
      bf16x8 bv[4];
#pragma unroll
      for (int ni=0; ni<4; ++ni){
        int nt = wave*4 + ni;
        bv[ni] = *(const bf16x8*)(lB + (((ks*16 + nt)*4 + quad)*16 + l15)*8);
      }
#pragma unroll
      for (int mi=0; mi<4; ++mi){
        bf16x8 av = *(const bf16x8*)(lA + (((ks*4 + mi)*4 + quad)*16 + l15)*8);
#pragma unroll
        for (int ni=0; ni<4; ++ni) acc[mi][ni] = MFMA16x16x32(av, bv[ni], acc[mi][ni]);
      }
    }
    __syncthreads();
  }
#pragma unroll
  for (int mi=0; mi<4; ++mi){
#pragma unroll
    for (int ni=0; ni<4; ++ni){
      int n = wave*64 + ni*16 + l15;
      int qy = n >> 4, qx = n & 15;
#pragma unroll
      for (int r=0; r<4; ++r){
        int m = mi*16 + quad*4 + r;
        int py = m >> 3, pxx = m & 7;
        int dy = qy - py, dx = qx - pxx;
        if ((unsigned)dy <= 8u && (unsigned)dx <= 8u)
          corr[(((b*64 + h0+py)*64) + (w0+pxx))*81 + dy*9 + dx] = acc[mi][ni][r];
      }
    }
  }
}

// ---------------------------------------------------------------------------
__global__ __launch_bounds__(256) void k_offset(const float* __restrict__ corr,
    const float* __restrict__ woff, float* __restrict__ offs){
  __shared__ float lc[32*84];
  __shared__ float lw[18*84];
  int tid = threadIdx.x, blk = blockIdx.x;
  int row = blk >> 1, half = blk & 1;
  int base = row*5184 + half*32*81;
  for (int i = tid; i < 32*81; i += 256){
    int px = i / 81, d = i % 81;
    lc[px*84 + d] = corr[base + i];
  }
  for (int i = tid; i < 18*84; i += 256){
    int o = i / 84, d = i % 84;
    if (d < 81) lw[i] = woff[o*81 + d];
  }
  __syncthreads();
  int px = tid & 31, og = tid >> 5;
  for (int o = og; o < 18; o += 8){
    float s = 0.f;
#pragma unroll
    for (int dd = 0; dd < 20; ++dd){
      float4 a = *(const float4*)(lc + px*84 + dd*4);
      float4 wv = *(const float4*)(lw + o*84 + dd*4);
      s += a.x*wv.x + a.y*wv.y + a.z*wv.z + a.w*wv.w;
    }
    s += lc[px*84 + 80] * lw[o*84 + 80];
    offs[(row*64 + half*32 + px)*18 + o] = s;
  }
}

// ---------------------------------------------------------------------------
// Deformable conv (unchanged).
__global__ __launch_bounds__(256) void k_deform(const u16* __restrict__ x2pad,
    const float* __restrict__ offs, const u16* __restrict__ walign,
    u16* __restrict__ stacked){
  __shared__ u16 lA[16384];
  int tid = threadIdx.x, bh = blockIdx.x;
  int b = bh >> 6, h = bh & 63;
  int wave = tid >> 6, lane = tid & 63, l15 = lane & 15, quad = lane >> 4;
  int px = tid >> 2, cg = tid & 3;
  int mt_s = px >> 4, ml_s = px & 15;
  f32x4 acc[4][4];
#pragma unroll
  for (int i=0;i<4;i++)
#pragma unroll
    for (int j=0;j<4;j++){ f32x4 z = {0.f,0.f,0.f,0.f}; acc[i][j] = z; }

  for (int tap = 0; tap < 9; ++tap){
    int ky = tap/3, kx = tap%3;
    float offy = offs[(bh*64 + px)*18 + 2*tap];
    float offx = offs[(bh*64 + px)*18 + 2*tap + 1];
    float y = (float)(h + ky - 1) + offy;
    float x = (float)(px + kx - 1) + offx;
    float y0f = floorf(y), x0f = floorf(x);
    float wy1 = y - y0f, wx1 = x - x0f;
    float wy0 = 1.f - wy1, wx0 = 1.f - wx1;
    int iy0 = iclampi((int)y0f, -4, 67), ix0 = iclampi((int)x0f, -4, 67);
    int iy1 = iclampi((int)y0f + 1, -4, 67), ix1 = iclampi((int)x0f + 1, -4, 67);
    const u16* p00 = x2pad + (((b*72 + iy0+4)*72) + (ix0+4))*256 + cg*64;
    const u16* p01 = x2pad + (((b*72 + iy0+4)*72) + (ix1+4))*256 + cg*64;
    const u16* p10 = x2pad + (((b*72 + iy1+4)*72) + (ix0+4))*256 + cg*64;
    const u16* p11 = x2pad + (((b*72 + iy1+4)*72) + (ix1+4))*256 + cg*64;
    float w00 = wy0*wx0, w01 = wy0*wx1, w10 = wy1*wx0, w11 = wy1*wx1;
#pragma unroll
    for (int u = 0; u < 8; ++u){
      int4 v00 = *(const int4*)(p00 + u*8);
      int4 v01 = *(const int4*)(p01 + u*8);
      int4 v10 = *(const int4*)(p10 + u*8);
      int4 v11 = *(const int4*)(p11 + u*8);
      float a00[8], a01[8], a10[8], a11[8];
      unpack8(v00,a00); unpack8(v01,a01); unpack8(v10,a10); unpack8(v11,a11);
      union { u16 h2[8]; int4 v; } R;
#pragma unroll
      for (int jj = 0; jj < 8; ++jj)
        R.h2[jj] = f2bf(w00*a00[jj] + w01*a01[jj] + w10*a10[jj] + w11*a11[jj]);
      int ch = cg*64 + u*8;
      int ks = ch >> 5, q = (ch >> 3) & 3;
      *(int4*)(lA + (((ks*4 + mt_s)*4 + q)*16 + ml_s)*8) = R.v;
    }
    __syncthreads();
#pragma unroll
    for (int ks = 0; ks < 8; ++ks){
      bf16x8 bv[4];
#pragma unroll
      for (int ni=0; ni<4; ++ni){
        int n = wave*64 + ni*16 + l15;
        bv[ni] = *(const bf16x8*)(walign + n*2304 + tap*256 + ks*32 + quad*8);
      }
#pragma unroll
      for (int mi=0; mi<4; ++mi){
        bf16x8 av = *(const bf16x8*)(lA + (((ks*4 + mi)*4 + quad)*16 + l15)*8);
#pragma unroll
        for (int ni=0; ni<4; ++ni) acc[mi][ni] = MFMA16x16x32(av, bv[ni], acc[mi][ni]);
      }
    }
    __syncthreads();
  }
#pragma unroll
  for (int mi=0; mi<4; ++mi){
#pragma unroll
    for (int ni=0; ni<4; ++ni){
      int n = wave*64 + ni*16 + l15;
#pragma unroll
      for (int r=0; r<4; ++r){
        int m = mi*16 + quad*4 + r;
        stacked[(((b*66 + h+1)*66) + (m+1))*512 + 256 + n] = f2bf(acc[mi][ni][r]);
      }
    }
  }
}

// ---------------------------------------------------------------------------
// Staging helpers for the 8-phase conv. All preserve the global_load_lds
// requirement: LDS slot j = (wave-uniform constant) + lane, so dest is
// uniform-base + lane*16.
__device__ __forceinline__ void stageA_half(u16* __restrict__ dst,
    const u16* __restrict__ in, int b, int h0, int kk, int hh, int tid){
  int tap = kk >> 3, ksin = kk & 7;
  int ky = tap/3, kx = tap - ky*3;
  const u16* abase = in + ((b*66 + h0 + ky)*66 + kx)*512 + ksin*64;
#pragma unroll
  for (int i = 0; i < 2; ++i){
    int pi = (tid >> 8)*2 + i;
    int ks2 = pi >> 1, blk = pi & 1;
    int j = (ks2<<10) | (blk<<9) | (hh<<8) | (tid & 255);
    int l = j & 15, q = (j >> 4) & 3;
    int t16 = ((j >> 6) & 3) | (hh<<2) | (blk<<3);
    int px = t16*16 + l, r = px >> 6, w = px & 63;
    g2l16(abase + (r*66 + w)*512 + ks2*32 + q*8, dst + j*8);
  }
}
__device__ __forceinline__ void stageB16_half(u16* __restrict__ dst,
    const u16* __restrict__ wts, int nb, int kk, int hh, int tid){
  const u16* wch = wts + (size_t)(kk*2 + nb) * 16384;
#pragma unroll
  for (int i = 0; i < 2; ++i){
    int j = (i<<10) | ((tid>>7)<<8) | (hh<<7) | (tid & 127);
    g2l16(wch + j*8, dst + j*8);
  }
}
__device__ __forceinline__ void stageB8(u16* __restrict__ dst,
    const u16* __restrict__ wts, int nb, int kk, int tid){
  const u16* wch = wts + (size_t)(kk*2 + nb) * 8192;
#pragma unroll
  for (int i = 0; i < 2; ++i){
    int j = (i<<9) | tid;
    g2l16(wch + j*8, dst + j*8);
  }
}

// One phase: {12 ds_read ; stage gloads ; barrier ; lgkm(0) ; 16 MFMA ;
// counted vmcnt ; barrier}. The phase-end vmcnt covers the NEXT phase's
// ds_reads; the closing s_barrier globalizes it across waves.
#define PHASE(QM, QN, WV, STG_STMT) do { \
  bf16x8 av_[4][2], bv_[2][2]; \
  _Pragma("unroll") \
  for (int m4=0;m4<4;++m4){ \
    _Pragma("unroll") \
    for (int k2=0;k2<2;++k2){ \
      int mrow = wm*8 + (QM)*4 + m4; \
      av_[m4][k2] = *(const bf16x8*)(Acur + (((k2*16 + mrow)*4 + quad)*16 + l15)*8); \
    } } \
  _Pragma("unroll") \
  for (int n2=0;n2<2;++n2){ \
    _Pragma("unroll") \
    for (int k2=0;k2<2;++k2){ \
      int ntl = wn*NI + (QN)*2 + n2; \
      bv_[n2][k2] = *(const bf16x8*)(Bcur + (((k2*NT + ntl)*4 + quad)*16 + l15)*8); \
    } } \
  STG_STMT; \
  asm volatile("" ::: "memory"); \
  __builtin_amdgcn_s_barrier(); \
  asm volatile("s_waitcnt lgkmcnt(0)" ::: "memory"); \
  __builtin_amdgcn_sched_barrier(0); \
  __builtin_amdgcn_s_setprio(1); \
  _Pragma("unroll") \
  for (int k2=0;k2<2;++k2){ \
    _Pragma("unroll") \
    for (int m4=0;m4<4;++m4){ \
      _Pragma("unroll") \
      for (int n2=0;n2<2;++n2){ \
        acc[(QM)*4+m4][(QN)*2+n2] = \
          MFMA16x16x32(av_[m4][k2], bv_[n2][k2], acc[(QM)*4+m4][(QN)*2+n2]); \
      } } } \
  __builtin_amdgcn_s_setprio(0); \
  __builtin_amdgcn_sched_barrier(0); \
  if (hasnext) { asm volatile("s_waitcnt vmcnt(" #WV ")" ::: "memory"); } \
  else         { asm volatile("s_waitcnt vmcnt(0)" ::: "memory"); } \
  asm volatile("" ::: "memory"); \
  __builtin_amdgcn_s_barrier(); \
} while(0)

// 3x3 conv, implicit GEMM, 256px x (NT*16)n tile, 8 waves (2M x 4N), BK=64.
// m201-style 8-phase schedule: 4 phases/K-tile (gate) computing one output
// quadrant each, lookahead-1 double buffer, counted vmcnt {2,6,6,4}.
template<int NT, bool STATS>
__global__ __launch_bounds__(512, 2) void k_conv256(const u16* __restrict__ in,
    const u16* __restrict__ wts, const float* __restrict__ bias,
    u16* __restrict__ outp, float* __restrict__ partials){
  constexpr int NI = NT / 4;
  __shared__ u16 lA[2][16384];      // 256 px x 64 ch per buffer
  __shared__ u16 lB[2][NT*1024];    // (NT*16) n x 64 ch per buffer

  int tid = threadIdx.x, g = blockIdx.x;
  int work = (g & 7) * 32 + (g >> 3);     // bijective XCD swizzle (256 % 8 == 0)
  int nb = work >> 7, mt = work & 127;    // nb-major: 32 works/XCD share B panel
  int b = mt >> 4, h0 = (mt & 15) * 4;
  int wave = tid >> 6, lane = tid & 63, l15 = lane & 15, quad = lane >> 4;
  int wm = wave & 1, wn = wave >> 1;

  f32x4 acc[8][NI];
#pragma unroll
  for (int i=0;i<8;i++)
#pragma unroll
    for (int j=0;j<NI;j++){ f32x4 z = {0.f,0.f,0.f,0.f}; acc[i][j] = z; }

  // Prologue: stage tile 0 into buf 0 in phase-group order, wait so that
  // phase-0 operands (groups 0,1) are resident, barrier to globalize.
  if constexpr (NT == 16){
    stageA_half(&lA[0][0], in, b, h0, 0, 0, tid);
    stageB16_half(&lB[0][0], wts, nb, 0, 0, tid);
    stageA_half(&lA[0][0], in, b, h0, 0, 1, tid);
    stageB16_half(&lB[0][0], wts, nb, 0, 1, tid);
    asm volatile("s_waitcnt vmcnt(4)" ::: "memory");
  } else {
    stageA_half(&lA[0][0], in, b, h0, 0, 0, tid);
    stageB8(&lB[0][0], wts, nb, 0, tid);
    stageA_half(&lA[0][0], in, b, h0, 0, 1, tid);
    asm volatile("s_waitcnt vmcnt(2)" ::: "memory");
  }
  asm volatile("" ::: "memory");
  __builtin_amdgcn_s_barrier();

#pragma unroll 1
  for (int t = 0; t < 72; ++t){
    int d = t & 1;
    const u16* Acur = &lA[d][0];
    const u16* Bcur = &lB[d][0];
    u16* Anext = &lA[d^1][0];
    u16* Bnext = &lB[d^1][0];
    bool hasnext = (t < 71);
    int kn = t + 1;
    if constexpr (NT == 16){
      PHASE(0,0,2, if (hasnext) stageA_half(Anext, in, b, h0, kn, 0, tid));
      PHASE(0,1,6, if (hasnext) stageB16_half(Bnext, wts, nb, kn, 0, tid));
      PHASE(1,0,6, if (hasnext) stageA_half(Anext, in, b, h0, kn, 1, tid));
      PHASE(1,1,4, if (hasnext) stageB16_half(Bnext, wts, nb, kn, 1, tid));
    } else {
      PHASE(0,0,4, if (hasnext){ stageA_half(Anext, in, b, h0, kn, 0, tid);
                                 stageB8(Bnext, wts, nb, kn, tid); });
      PHASE(1,0,2, if (hasnext) stageA_half(Anext, in, b, h0, kn, 1, tid));
    }
  }

  float bvl[NI];
#pragma unroll
  for (int ni = 0; ni < NI; ++ni)
    bvl[ni] = bias[nb*(NT*16) + wn*(NI*16) + ni*16 + l15];
  float sc = 0.f, ss = 0.f, sq = 0.f;
#pragma unroll
  for (int mi=0; mi<8; ++mi){
#pragma unroll
    for (int ni=0; ni<NI; ++ni){
      int n = nb*(NT*16) + wn*(NI*16) + ni*16 + l15;
#pragma unroll
      for (int r=0; r<4; ++r){
        int m = wm*128 + mi*16 + quad*4 + r;
        int row = h0 + (m >> 6), w = m & 63;
        float v = acc[mi][ni][r] + bvl[ni];
        v = fmaxf(v, 0.f);
        outp[(((b*64 + row)*64) + w)*(NT*32) + n] = f2bf(v);
        if (STATS){ sc += (v > 0.f) ? 1.f : 0.f; ss += v; sq += v*v; }
      }
    }
  }
  if constexpr (STATS){
    __shared__ float red[8][3];
#pragma unroll
    for (int off = 32; off; off >>= 1){
      sc += __shfl_down(sc, off); ss += __shfl_down(ss, off); sq += __shfl_down(sq, off);
    }
    if (lane == 0){ red[wave][0]=sc; red[wave][1]=ss; red[wave][2]=sq; }
    __syncthreads();
    if (tid == 0){
      float a0=0,a1=0,a2=0;
      for (int w2=0; w2<8; ++w2){ a0+=red[w2][0]; a1+=red[w2][1]; a2+=red[w2][2]; }
      partials[work*3+0]=a0; partials[work*3+1]=a1; partials[work*3+2]=a2;
    }
  }
}

// ---------------------------------------------------------------------------
// Reduce 256 per-work partials; work<128 -> update, else reset.
__global__ __launch_bounds__(256) void k_finalize(const float* __restrict__ partials,
                                                  float* __restrict__ ubs){
  __shared__ float red[4][6];
  int tid = threadIdx.x, lane = tid & 63, wave = tid >> 6;
  float cu=0,su=0,qu=0,cr=0,sr=0,qr=0;
  {
    float c = partials[tid*3+0], s = partials[tid*3+1], q = partials[tid*3+2];
    if (tid < 128){ cu=c; su=s; qu=q; } else { cr=c; sr=s; qr=q; }
  }
#pragma unroll
  for (int off = 32; off; off >>= 1){
    cu += __shfl_down(cu, off); su += __shfl_down(su, off); qu += __shfl_down(qu, off);
    cr += __shfl_down(cr, off); sr += __shfl_down(sr, off); qr += __shfl_down(qr, off);
  }
  if (lane == 0){ red[wave][0]=cu; red[wave][1]=su; red[wave][2]=qu;
                  red[wave][3]=cr; red[wave][4]=sr; red[wave][5]=qr; }
  __syncthreads();
  if (tid < 2){
    double C=0, S=0, Q=0;
    for (int w2=0; w2<4; ++w2){
      C += red[w2][tid*3+0]; S += red[w2][tid*3+1]; Q += red[w2][tid*3+2];
    }
    float ub = 1.f;
    if (C >= 2.0){
      double mean = S / C;
      double var = (Q - C*mean*mean) / (C - 1.0);
      if (var < 0.0) var = 0.0;
      ub = (float)(mean + 3.0*sqrt(var));
    }
    ubs[tid] = ub;
    ubs[2+tid] = 1.f/ub;
  }
}

// stacked2[...,256:512] = bf16(in_state * min(reset,ub_r)/ub_r)
__global__ __launch_bounds__(256) void k_mulreset(const u16* __restrict__ G,
    const u16* __restrict__ x2pad, const float* __restrict__ ubs,
    u16* __restrict__ stacked2){
  int tid = threadIdx.x, bh = blockIdx.x;
  int b = bh >> 6, h = bh & 63;
  int px = tid >> 2, cg = tid & 3;
  float ubr = ubs[1], inv = ubs[3];
#pragma unroll
  for (int u = 0; u < 8; ++u){
    int c = cg*64 + u*8;
    int4 gv = *(const int4*)(G + (bh*64 + px)*512 + 256 + c);
    int4 sv = *(const int4*)(x2pad + (((b*72 + h+4)*72) + (px+4))*256 + c);
    float gf[8], sf[8]; unpack8(gv, gf); unpack8(sv, sf);
    union { u16 h2[8]; int4 v; } R;
#pragma unroll
    for (int j=0;j<8;j++){
      float r = fminf(gf[j], ubr) * inv;
      R.h2[j] = f2bf(sf[j] * r);
    }
    *(int4*)(stacked2 + (((b*66 + h+1)*66) + (px+1))*512 + 256 + c) = R.v;
  }
}

// new_state = s*(1-u) + o*u, NCHW fp32 out (x2 copies), via LDS transpose.
__global__ __launch_bounds__(256) void k_final(const u16* __restrict__ G,
    const u16* __restrict__ O, const float* __restrict__ in_state,
    const float* __restrict__ ubs, float* __restrict__ dout){
  __shared__ float Q[64*65];
  __shared__ float P[64*65];
  int tid = threadIdx.x, bh = blockIdx.x;
  int b = bh >> 6, h = bh & 63;
  float ubu = ubs[0], inv = ubs[2];
  int px = tid >> 2, cs = (tid & 3)*16;
  int w = tid & 63, c4 = tid >> 6;
  for (int cb = 0; cb < 4; ++cb){
#pragma unroll
    for (int tt = 0; tt < 2; ++tt){
      int cl = cs + tt*8;
      int c = cb*64 + cl;
      int4 gv = *(const int4*)(G + (bh*64 + px)*512 + c);
      int4 ov = *(const int4*)(O + (bh*64 + px)*256 + c);
      float gf[8], of[8]; unpack8(gv, gf); unpack8(ov, of);
#pragma unroll
      for (int j=0;j<8;j++){
        float u = fminf(gf[j], ubu) * inv;
        Q[px*65 + cl + j] = u;
        P[px*65 + cl + j] = of[j]*u;
      }
    }
    __syncthreads();
    for (int i = 0; i < 16; ++i){
      int cl = i*4 + c4;
      int c = cb*64 + cl;
      int gidx = (((b*256 + c)*64) + h)*64 + w;
      float s = in_state[gidx];
      float v = s*(1.f - Q[w*65 + cl]) + P[w*65 + cl];
      dout[gidx] = v;
      dout[8388608 + gidx] = v;
    }
    __syncthreads();
  }
}

// ---------------------------------------------------------------------------
extern "C" void kernel_launch(void* const* d_in, const int* in_sizes, int n_in,
                              void* d_out, int out_size, void* d_ws, size_t ws_size,
                              hipStream_t stream){
  (void)in_sizes; (void)n_in; (void)out_size; (void)ws_size;
  const float* inputs   = (const float*)d_in[0];
  const float* in_state = (const float*)d_in[1];
  const float* w_reset  = (const float*)d_in[2];
  const float* b_reset  = (const float*)d_in[3];
  const float* w_update = (const float*)d_in[4];
  const float* b_update = (const float*)d_in[5];
  const float* w_out    = (const float*)d_in[6];
  const float* b_out    = (const float*)d_in[7];
  const float* w_offset = (const float*)d_in[8];
  const float* w_align  = (const float*)d_in[9];
  float* dout = (float*)d_out;

  char* ws = (char*)d_ws;
  size_t off = 0;
  auto alloc = [&](size_t bytes)->char*{
    char* p = ws + off; off = (off + bytes + 255) & ~(size_t)255; return p;
  };
  const size_t x2pad_b   = 8ull*72*72*256*2;
  const size_t stacked_b = 8ull*66*66*512*2;
  u16* x2pad    = (u16*)alloc(x2pad_b);
  u16* stacked  = (u16*)alloc(stacked_b);
  u16* stacked2 = (u16*)alloc(stacked_b);
  float* corr   = (float*)alloc(8ull*64*64*81*4);
  float* offs   = (float*)alloc(8ull*64*64*18*4);
  u16* G        = (u16*)alloc(8ull*64*64*512*2);
  u16* O        = (u16*)alloc(8ull*64*64*256*2);
  u16* wgate    = (u16*)alloc(512ull*4608*2);
  u16* woutb    = (u16*)alloc(256ull*4608*2);
  u16* walignb  = (u16*)alloc(256ull*2304*2);
  float* woff   = (float*)alloc(1458*4);
  float* biascat= (float*)alloc(512*4);
  float* partials=(float*)alloc(1024*3*4);
  float* ubs    = (float*)alloc(4*4);

  hipMemsetAsync(x2pad,    0, x2pad_b,   stream);
  hipMemsetAsync(stacked,  0, stacked_b, stream);
  hipMemsetAsync(stacked2, 0, stacked_b, stream);

  k_repack<<<9216, 256, 0, stream>>>(w_reset, b_reset, w_update, b_update, w_out,
                                     w_offset, w_align, wgate, woutb, walignb, woff, biascat);
  k_transform<<<512, 256, 0, stream>>>(inputs, in_state, stacked, stacked2, x2pad);
  k_corr<<<512, 256, 0, stream>>>(stacked, x2pad, corr);
  k_offset<<<1024, 256, 0, stream>>>(corr, woff, offs);
  k_deform<<<512, 256, 0, stream>>>(x2pad, offs, walignb, stacked);
  k_conv256<16, true><<<256, 512, 0, stream>>>(stacked, wgate, biascat, G, partials);
  k_finalize<<<1, 256, 0, stream>>>(partials, ubs);
  k_mulreset<<<512, 256, 0, stream>>>(G, x2pad, ubs, stacked2);
  k_conv256<8, false><<<256, 512, 0, stream>>>(stacked2, woutb, b_out, O, nullptr);
  k_final<<<512, 256, 0, stream>>>(G, O, in_state, ubs, dout);
}

// Round 3
// 669.387 us; speedup vs baseline: 1.0486x; 1.0486x over previous
//
#include <hip/hip_runtime.h>
#include <stdint.h>
#include <math.h>

typedef unsigned short u16;
typedef short bf16x8 __attribute__((ext_vector_type(8)));
typedef float f32x4 __attribute__((ext_vector_type(4)));

#define MFMA16x16x32(a,b,c) __builtin_amdgcn_mfma_f32_16x16x32_bf16((a),(b),(c),0,0,0)

typedef __attribute__((address_space(3))) void as3_void;
typedef const __attribute__((address_space(1))) void as1_void;

__device__ __forceinline__ void g2l16(const void* g, void* l){
#if __has_builtin(__builtin_amdgcn_global_load_lds)
  __builtin_amdgcn_global_load_lds((as1_void*)g, (as3_void*)l, 16, 0, 0);
#else
  *(int4*)l = *(const int4*)g;
#endif
}

__device__ __forceinline__ u16 f2bf(float f){
  uint32_t u = __builtin_bit_cast(uint32_t, f);
  u += 0x7fffu + ((u >> 16) & 1u);
  return (u16)(u >> 16);
}
__device__ __forceinline__ float bf2f(u16 h){
  uint32_t u = ((uint32_t)h) << 16;
  return __builtin_bit_cast(float, u);
}
__device__ __forceinline__ void unpack8(int4 v, float* o){
  uint32_t w0=(uint32_t)v.x, w1=(uint32_t)v.y, w2=(uint32_t)v.z, w3=(uint32_t)v.w;
  o[0]=__builtin_bit_cast(float, w0<<16); o[1]=__builtin_bit_cast(float, w0&0xffff0000u);
  o[2]=__builtin_bit_cast(float, w1<<16); o[3]=__builtin_bit_cast(float, w1&0xffff0000u);
  o[4]=__builtin_bit_cast(float, w2<<16); o[5]=__builtin_bit_cast(float, w2&0xffff0000u);
  o[6]=__builtin_bit_cast(float, w3<<16); o[7]=__builtin_bit_cast(float, w3&0xffff0000u);
}
__device__ __forceinline__ int iclampi(int v,int lo,int hi){ return v<lo?lo:(v>hi?hi:v); }

// ---------------------------------------------------------------------------
// Weights frag-packed per K-tile-64 chunk (identical layout to round 2).
__global__ void k_repack(const float* __restrict__ w_reset, const float* __restrict__ b_reset,
                         const float* __restrict__ w_update, const float* __restrict__ b_update,
                         const float* __restrict__ w_out, const float* __restrict__ w_offset,
                         const float* __restrict__ w_align,
                         u16* __restrict__ wgate, u16* __restrict__ wout,
                         u16* __restrict__ walign, float* __restrict__ woff,
                         float* __restrict__ biascat){
  int idx = blockIdx.x * 256 + threadIdx.x;
  if (idx < 512*4608){           // gate: BN=256, nb in {0,1}
    int e = idx & 7, j = (idx >> 3) & 2047, chunk = idx >> 14;
    int nb = chunk & 1, kk = chunk >> 1;
    int l = j & 15, q = (j >> 4) & 3, t16 = (j >> 6) & 15, ks2 = j >> 10;
    int n = nb*256 + t16*16 + l;
    int tap = kk >> 3, ksin = kk & 7;
    int c = ksin*64 + ks2*32 + q*8 + e;
    int ky = tap/3, kx = tap%3;
    float v = (n < 256) ? w_update[((n*512 + c)*3 + ky)*3 + kx]
                        : w_reset[(((n-256)*512 + c)*3 + ky)*3 + kx];
    wgate[idx] = f2bf(v);
  }
  if (idx < 256*4608){           // out: BN=128, nb in {0,1}
    int e = idx & 7, j = (idx >> 3) & 1023, chunk = idx >> 13;
    int nb = chunk & 1, kk = chunk >> 1;
    int l = j & 15, q = (j >> 4) & 3, t8 = (j >> 6) & 7, ks2 = j >> 9;
    int n = nb*128 + t8*16 + l;
    int tap = kk >> 3, ksin = kk & 7;
    int c = ksin*64 + ks2*32 + q*8 + e;
    int ky = tap/3, kx = tap%3;
    wout[idx] = f2bf(w_out[((n*512 + c)*3 + ky)*3 + kx]);
  }
  if (idx < 256*2304){           // align (k_deform reads directly)
    int n = idx / 2304, k = idx % 2304;
    int tap = k >> 8, c = k & 255;
    int ky = tap/3, kx = tap%3;
    walign[idx] = f2bf(w_align[((n*256 + c)*3 + ky)*3 + kx]);
  }
  if (idx < 1458) woff[idx] = w_offset[idx] * (1.f/256.f);
  if (idx < 512) biascat[idx] = (idx < 256) ? b_update[idx] : b_reset[idx-256];
}

// ---------------------------------------------------------------------------
// NCHW fp32 -> NHWC bf16.
__global__ __launch_bounds__(256) void k_transform(const float* __restrict__ inputs,
    const float* __restrict__ in_state, u16* __restrict__ stacked,
    u16* __restrict__ stacked2, u16* __restrict__ x2pad){
  __shared__ u16 t1[64*264];
  __shared__ u16 t2[64*264];
  int tid = threadIdx.x, bh = blockIdx.x;
  int b = bh >> 6, h = bh & 63;
  int w = tid & 63, cq = tid >> 6;
  for (int i = 0; i < 64; ++i){
    int c = i*4 + cq;
    int gi = ((b*256 + c)*64 + h)*64 + w;
    t1[w*264 + c] = f2bf(inputs[gi]);
    t2[w*264 + c] = f2bf(in_state[gi]);
  }
  __syncthreads();
  int px = tid >> 2, cg = tid & 3;
#pragma unroll
  for (int u = 0; u < 8; ++u){
    int c = cg*64 + u*8;
    int4 v1 = *(const int4*)(t1 + px*264 + c);
    int4 v2 = *(const int4*)(t2 + px*264 + c);
    *(int4*)(stacked  + (((b*66 + h+1)*66) + (px+1))*512 + c) = v1;
    *(int4*)(stacked2 + (((b*66 + h+1)*66) + (px+1))*512 + c) = v1;
    *(int4*)(x2pad    + (((b*72 + h+4)*72) + (px+4))*256 + c) = v2;
  }
}

// ---------------------------------------------------------------------------
// Correlation as masked local GEMM.
__global__ __launch_bounds__(256) void k_corr(const u16* __restrict__ stacked,
    const u16* __restrict__ x2pad, float* __restrict__ corr){
  __shared__ u16 lA[8192];
  __shared__ u16 lB[32768];
  int tid = threadIdx.x, idx = blockIdx.x;
  int b = idx >> 6, ty = (idx >> 3) & 7, tx = idx & 7;
  int h0 = ty*8, w0 = tx*8;
  int wave = tid >> 6, lane = tid & 63, l15 = lane & 15, quad = lane >> 4;
  f32x4 acc[4][4];
#pragma unroll
  for (int i=0;i<4;i++)
#pragma unroll
    for (int j=0;j<4;j++){ f32x4 z = {0.f,0.f,0.f,0.f}; acc[i][j] = z; }

  for (int s = 0; s < 2; ++s){
#pragma unroll
    for (int i = 0; i < 4; ++i){
      int j = tid + i*256;
      int ml = j & 15, q = (j>>4)&3, mt = (j>>6)&3, ks = j >> 8;
      int px = mt*16 + ml, py = px >> 3, pxx = px & 7;
      const u16* g = stacked + (((b*66 + h0+py+1)*66) + (w0+pxx+1))*512 + s*128 + ks*32 + q*8;
      g2l16(g, lA + j*8);
    }
#pragma unroll
    for (int i = 0; i < 16; ++i){
      int j = tid + i*256;
      int nl = j & 15, q = (j>>4)&3, nt = (j>>6)&15, ks = j >> 10;
      int qp = nt*16 + nl, qy = qp >> 4, qx = qp & 15;
      const u16* g = x2pad + (((b*72 + h0+qy)*72) + (w0+qx))*256 + s*128 + ks*32 + q*8;
      g2l16(g, lB + j*8);
    }
    __syncthreads();
#pragma unroll
    for (int ks = 0; ks < 4; ++ks){
      bf16x8 bv[4];
#pragma unroll
      for (int ni=0; ni<4; ++ni){
        int nt = wave*4 + ni;
        bv[ni] = *(const bf16x8*)(lB + (((ks*16 + nt)*4 + quad)*16 + l15)*8);
      }
#pragma unroll
      for (int mi=0; mi<4; ++mi){
        bf16x8 av = *(const bf16x8*)(lA + (((ks*4 + mi)*4 + quad)*16 + l15)*8);
#pragma unroll
        for (int ni=0; ni<4; ++ni) acc[mi][ni] = MFMA16x16x32(av, bv[ni], acc[mi][ni]);
      }
    }
    __syncthreads();
  }
#pragma unroll
  for (int mi=0; mi<4; ++mi){
#pragma unroll
    for (int ni=0; ni<4; ++ni){
      int n = wave*64 + ni*16 + l15;
      int qy = n >> 4, qx = n & 15;
#pragma unroll
      for (int r=0; r<4; ++r){
        int m = mi*16 + quad*4 + r;
        int py = m >> 3, pxx = m & 7;
        int dy = qy - py, dx = qx - pxx;
        if ((unsigned)dy <= 8u && (unsigned)dx <= 8u)
          corr[(((b*64 + h0+py)*64) + (w0+pxx))*81 + dy*9 + dx] = acc[mi][ni][r];
      }
    }
  }
}

// ---------------------------------------------------------------------------
__global__ __launch_bounds__(256) void k_offset(const float* __restrict__ corr,
    const float* __restrict__ woff, float* __restrict__ offs){
  __shared__ float lc[32*84];
  __shared__ float lw[18*84];
  int tid = threadIdx.x, blk = blockIdx.x;
  int row = blk >> 1, half = blk & 1;
  int base = row*5184 + half*32*81;
  for (int i = tid; i < 32*81; i += 256){
    int px = i / 81, d = i % 81;
    lc[px*84 + d] = corr[base + i];
  }
  for (int i = tid; i < 18*84; i += 256){
    int o = i / 84, d = i % 84;
    if (d < 81) lw[i] = woff[o*81 + d];
  }
  __syncthreads();
  int px = tid & 31, og = tid >> 5;
  for (int o = og; o < 18; o += 8){
    float s = 0.f;
#pragma unroll
    for (int dd = 0; dd < 20; ++dd){
      float4 a = *(const float4*)(lc + px*84 + dd*4);
      float4 wv = *(const float4*)(lw + o*84 + dd*4);
      s += a.x*wv.x + a.y*wv.y + a.z*wv.z + a.w*wv.w;
    }
    s += lc[px*84 + 80] * lw[o*84 + 80];
    offs[(row*64 + half*32 + px)*18 + o] = s;
  }
}

// ---------------------------------------------------------------------------
// Deformable conv (unchanged).
__global__ __launch_bounds__(256) void k_deform(const u16* __restrict__ x2pad,
    const float* __restrict__ offs, const u16* __restrict__ walign,
    u16* __restrict__ stacked){
  __shared__ u16 lA[16384];
  int tid = threadIdx.x, bh = blockIdx.x;
  int b = bh >> 6, h = bh & 63;
  int wave = tid >> 6, lane = tid & 63, l15 = lane & 15, quad = lane >> 4;
  int px = tid >> 2, cg = tid & 3;
  int mt_s = px >> 4, ml_s = px & 15;
  f32x4 acc[4][4];
#pragma unroll
  for (int i=0;i<4;i++)
#pragma unroll
    for (int j=0;j<4;j++){ f32x4 z = {0.f,0.f,0.f,0.f}; acc[i][j] = z; }

  for (int tap = 0; tap < 9; ++tap){
    int ky = tap/3, kx = tap%3;
    float offy = offs[(bh*64 + px)*18 + 2*tap];
    float offx = offs[(bh*64 + px)*18 + 2*tap + 1];
    float y = (float)(h + ky - 1) + offy;
    float x = (float)(px + kx - 1) + offx;
    float y0f = floorf(y), x0f = floorf(x);
    float wy1 = y - y0f, wx1 = x - x0f;
    float wy0 = 1.f - wy1, wx0 = 1.f - wx1;
    int iy0 = iclampi((int)y0f, -4, 67), ix0 = iclampi((int)x0f, -4, 67);
    int iy1 = iclampi((int)y0f + 1, -4, 67), ix1 = iclampi((int)x0f + 1, -4, 67);
    const u16* p00 = x2pad + (((b*72 + iy0+4)*72) + (ix0+4))*256 + cg*64;
    const u16* p01 = x2pad + (((b*72 + iy0+4)*72) + (ix1+4))*256 + cg*64;
    const u16* p10 = x2pad + (((b*72 + iy1+4)*72) + (ix0+4))*256 + cg*64;
    const u16* p11 = x2pad + (((b*72 + iy1+4)*72) + (ix1+4))*256 + cg*64;
    float w00 = wy0*wx0, w01 = wy0*wx1, w10 = wy1*wx0, w11 = wy1*wx1;
#pragma unroll
    for (int u = 0; u < 8; ++u){
      int4 v00 = *(const int4*)(p00 + u*8);
      int4 v01 = *(const int4*)(p01 + u*8);
      int4 v10 = *(const int4*)(p10 + u*8);
      int4 v11 = *(const int4*)(p11 + u*8);
      float a00[8], a01[8], a10[8], a11[8];
      unpack8(v00,a00); unpack8(v01,a01); unpack8(v10,a10); unpack8(v11,a11);
      union { u16 h2[8]; int4 v; } R;
#pragma unroll
      for (int jj = 0; jj < 8; ++jj)
        R.h2[jj] = f2bf(w00*a00[jj] + w01*a01[jj] + w10*a10[jj] + w11*a11[jj]);
      int ch = cg*64 + u*8;
      int ks = ch >> 5, q = (ch >> 3) & 3;
      *(int4*)(lA + (((ks*4 + mt_s)*4 + q)*16 + ml_s)*8) = R.v;
    }
    __syncthreads();
#pragma unroll
    for (int ks = 0; ks < 8; ++ks){
      bf16x8 bv[4];
#pragma unroll
      for (int ni=0; ni<4; ++ni){
        int n = wave*64 + ni*16 + l15;
        bv[ni] = *(const bf16x8*)(walign + n*2304 + tap*256 + ks*32 + quad*8);
      }
#pragma unroll
      for (int mi=0; mi<4; ++mi){
        bf16x8 av = *(const bf16x8*)(lA + (((ks*4 + mi)*4 + quad)*16 + l15)*8);
#pragma unroll
        for (int ni=0; ni<4; ++ni) acc[mi][ni] = MFMA16x16x32(av, bv[ni], acc[mi][ni]);
      }
    }
    __syncthreads();
  }
#pragma unroll
  for (int mi=0; mi<4; ++mi){
#pragma unroll
    for (int ni=0; ni<4; ++ni){
      int n = wave*64 + ni*16 + l15;
#pragma unroll
      for (int r=0; r<4; ++r){
        int m = mi*16 + quad*4 + r;
        stacked[(((b*66 + h+1)*66) + (m+1))*512 + 256 + n] = f2bf(acc[mi][ni][r]);
      }
    }
  }
}

// ---------------------------------------------------------------------------
// Staging: split by ks2 (K-half). Slot j = const | tid -> LDS dest is
// wave-uniform base + lane*16 (global_load_lds requirement).
__device__ __forceinline__ void stageA_k(u16* __restrict__ dst,
    const u16* __restrict__ in, int b, int h0, int kk, int ks2, int tid){
  int tap = kk >> 3, ksin = kk & 7;
  int ky = tap/3, kx = tap - ky*3;
  const u16* abase = in + ((b*66 + h0 + ky)*66 + kx)*512 + ksin*64 + ks2*32;
#pragma unroll
  for (int i = 0; i < 2; ++i){
    int j = (ks2<<10) | (i<<9) | tid;
    int l = j & 15, q = (j >> 4) & 3, t16 = (j >> 6) & 15;
    int px = t16*16 + l, r = px >> 6, w = px & 63;
    g2l16(abase + (r*66 + w)*512 + q*8, dst + j*8);
  }
}
__device__ __forceinline__ void stageB16_k(u16* __restrict__ dst,
    const u16* __restrict__ wts, int nb, int kk, int ks2, int tid){
  const u16* wch = wts + (size_t)(kk*2 + nb) * 16384;
#pragma unroll
  for (int i = 0; i < 2; ++i){
    int j = (ks2<<10) | (i<<9) | tid;
    g2l16(wch + j*8, dst + j*8);
  }
}
__device__ __forceinline__ void stageB8_k(u16* __restrict__ dst,
    const u16* __restrict__ wts, int nb, int kk, int ks2, int tid){
  const u16* wch = wts + (size_t)(kk*2 + nb) * 8192;
  int j = (ks2<<9) | tid;
  g2l16(wch + j*8, dst + j*8);
}

// Phase (NT=16): non-redundant register subtiles. LOADB phases refresh bv_
// (shared across the following phase); av_ streamed per phase. 16 MFMA per
// barrier pair. Counted vmcnt (WV>=0) sits before the closing barrier so the
// barrier globalizes the wait across waves.
#define PHASE16(MH, K2, LOADB, STG_STMT, WV) do { \
  bf16x8 av_[4]; \
  _Pragma("unroll") \
  for (int m4=0;m4<4;++m4) \
    av_[m4] = *(const bf16x8*)(Acur + ((((K2)*16 + wm*8 + (MH)*4 + m4)*4 + quad)*16 + l15)*8); \
  if constexpr (LOADB){ \
    _Pragma("unroll") \
    for (int ni=0;ni<4;++ni) \
      bv_[ni] = *(const bf16x8*)(Bcur + ((((K2)*16 + wn*4 + ni)*4 + quad)*16 + l15)*8); \
  } \
  STG_STMT; \
  asm volatile("" ::: "memory"); \
  __builtin_amdgcn_s_barrier(); \
  asm volatile("s_waitcnt lgkmcnt(0)" ::: "memory"); \
  __builtin_amdgcn_sched_barrier(0); \
  __builtin_amdgcn_s_setprio(1); \
  _Pragma("unroll") \
  for (int m4=0;m4<4;++m4){ \
    _Pragma("unroll") \
    for (int ni=0;ni<4;++ni) \
      acc[(MH)*4+m4][ni] = MFMA16x16x32(av_[m4], bv_[ni], acc[(MH)*4+m4][ni]); \
  } \
  __builtin_amdgcn_s_setprio(0); \
  __builtin_amdgcn_sched_barrier(0); \
  if ((WV) >= 0){ \
    if (hasnext) { asm volatile("s_waitcnt vmcnt(%0)" :: "i"((WV) < 0 ? 0 : (WV)) : "memory"); } \
    else         { asm volatile("s_waitcnt vmcnt(0)" ::: "memory"); } \
  } \
  asm volatile("" ::: "memory"); \
  __builtin_amdgcn_s_barrier(); \
} while(0)

// Phase (NT=8): 2 phases per K-tile, one K-half each, 16 MFMA per phase.
#define PHASE8(K2, STG_STMT, WV) do { \
  bf16x8 av_[8]; \
  _Pragma("unroll") \
  for (int m8=0;m8<8;++m8) \
    av_[m8] = *(const bf16x8*)(Acur + ((((K2)*16 + wm*8 + m8)*4 + quad)*16 + l15)*8); \
  _Pragma("unroll") \
  for (int ni=0;ni<2;++ni) \
    bv_[ni] = *(const bf16x8*)(Bcur + ((((K2)*8 + wn*2 + ni)*4 + quad)*16 + l15)*8); \
  STG_STMT; \
  asm volatile("" ::: "memory"); \
  __builtin_amdgcn_s_barrier(); \
  asm volatile("s_waitcnt lgkmcnt(0)" ::: "memory"); \
  __builtin_amdgcn_sched_barrier(0); \
  __builtin_amdgcn_s_setprio(1); \
  _Pragma("unroll") \
  for (int m8=0;m8<8;++m8){ \
    _Pragma("unroll") \
    for (int ni=0;ni<2;++ni) \
      acc[m8][ni] = MFMA16x16x32(av_[m8], bv_[ni], acc[m8][ni]); \
  } \
  __builtin_amdgcn_s_setprio(0); \
  __builtin_amdgcn_sched_barrier(0); \
  if (hasnext) { asm volatile("s_waitcnt vmcnt(%0)" :: "i"(WV) : "memory"); } \
  else         { asm volatile("s_waitcnt vmcnt(0)" ::: "memory"); } \
  asm volatile("" ::: "memory"); \
  __builtin_amdgcn_s_barrier(); \
} while(0)

// 3x3 conv, implicit GEMM, 256px x (NT*16)n tile, 8 waves (2M x 4N), BK=64.
// Fine phases by (k-half, m-half) — non-redundant ds_reads (24/wave/K-tile,
// as round 1) at m201's 16-MFMA-per-barrier granularity; lookahead-1 double
// buffer; 2 counted vmcnt per K-tile.
template<int NT, bool STATS>
__global__ __launch_bounds__(512, 2) void k_conv256(const u16* __restrict__ in,
    const u16* __restrict__ wts, const float* __restrict__ bias,
    u16* __restrict__ outp, float* __restrict__ partials){
  constexpr int NI = NT / 4;
  __shared__ u16 lA[2][16384];      // 256 px x 64 ch per buffer
  __shared__ u16 lB[2][NT*1024];    // (NT*16) n x 64 ch per buffer

  int tid = threadIdx.x, g = blockIdx.x;
  int work = (g & 7) * 32 + (g >> 3);     // bijective XCD swizzle (256 % 8 == 0)
  int nb = work >> 7, mt = work & 127;    // nb-major: 32 works/XCD share B panel
  int b = mt >> 4, h0 = (mt & 15) * 4;
  int wave = tid >> 6, lane = tid & 63, l15 = lane & 15, quad = lane >> 4;
  int wm = wave & 1, wn = wave >> 1;

  f32x4 acc[8][NI];
#pragma unroll
  for (int i=0;i<8;i++)
#pragma unroll
    for (int j=0;j<NI;j++){ f32x4 z = {0.f,0.f,0.f,0.f}; acc[i][j] = z; }

  // Prologue: stage tile 0 (group order gA0,gB0,gA1,gB1); retire gA0,gB0.
  if constexpr (NT == 16){
    stageA_k(&lA[0][0], in, b, h0, 0, 0, tid);
    stageB16_k(&lB[0][0], wts, nb, 0, 0, tid);
    stageA_k(&lA[0][0], in, b, h0, 0, 1, tid);
    stageB16_k(&lB[0][0], wts, nb, 0, 1, tid);
    asm volatile("s_waitcnt vmcnt(4)" ::: "memory");
  } else {
    stageA_k(&lA[0][0], in, b, h0, 0, 0, tid);
    stageB8_k(&lB[0][0], wts, nb, 0, 0, tid);
    stageA_k(&lA[0][0], in, b, h0, 0, 1, tid);
    stageB8_k(&lB[0][0], wts, nb, 0, 1, tid);
    asm volatile("s_waitcnt vmcnt(3)" ::: "memory");
  }
  asm volatile("" ::: "memory");
  __builtin_amdgcn_s_barrier();

#pragma unroll 1
  for (int t = 0; t < 72; ++t){
    int d = t & 1;
    const u16* Acur = &lA[d][0];
    const u16* Bcur = &lB[d][0];
    u16* Anext = &lA[d^1][0];
    u16* Bnext = &lB[d^1][0];
    bool hasnext = (t < 71);
    int kn = t + 1;
    if constexpr (NT == 16){
      bf16x8 bv_[4];
      // p0: k0, m-half0; loads bv[k0]; stages gA0(t+1)
      PHASE16(0, 0, 1, if (hasnext) stageA_k(Anext, in, b, h0, kn, 0, tid), -1);
      // p1: k0, m-half1; reuses bv_; stages gB0(t+1); W1 retires gA1,gB1(t)
      PHASE16(1, 0, 0, if (hasnext) stageB16_k(Bnext, wts, nb, kn, 0, tid), 4);
      // p2: k1, m-half0; loads bv[k1]; stages gA1(t+1)
      PHASE16(0, 1, 1, if (hasnext) stageA_k(Anext, in, b, h0, kn, 1, tid), -1);
      // p3: k1, m-half1; stages gB1(t+1); W3 retires gA0,gB0(t+1)
      PHASE16(1, 1, 0, if (hasnext) stageB16_k(Bnext, wts, nb, kn, 1, tid), 4);
    } else {
      bf16x8 bv_[2];
      PHASE8(0, if (hasnext){ stageA_k(Anext, in, b, h0, kn, 0, tid);
                              stageB8_k(Bnext, wts, nb, kn, 0, tid); }, 3);
      PHASE8(1, if (hasnext){ stageA_k(Anext, in, b, h0, kn, 1, tid);
                              stageB8_k(Bnext, wts, nb, kn, 1, tid); }, 3);
    }
  }

  float bvl[NI];
#pragma unroll
  for (int ni = 0; ni < NI; ++ni)
    bvl[ni] = bias[nb*(NT*16) + wn*(NI*16) + ni*16 + l15];
  float sc = 0.f, ss = 0.f, sq = 0.f;
#pragma unroll
  for (int mi=0; mi<8; ++mi){
#pragma unroll
    for (int ni=0; ni<NI; ++ni){
      int n = nb*(NT*16) + wn*(NI*16) + ni*16 + l15;
#pragma unroll
      for (int r=0; r<4; ++r){
        int m = wm*128 + mi*16 + quad*4 + r;
        int row = h0 + (m >> 6), w = m & 63;
        float v = acc[mi][ni][r] + bvl[ni];
        v = fmaxf(v, 0.f);
        outp[(((b*64 + row)*64) + w)*(NT*32) + n] = f2bf(v);
        if (STATS){ sc += (v > 0.f) ? 1.f : 0.f; ss += v; sq += v*v; }
      }
    }
  }
  if constexpr (STATS){
    __shared__ float red[8][3];
#pragma unroll
    for (int off = 32; off; off >>= 1){
      sc += __shfl_down(sc, off); ss += __shfl_down(ss, off); sq += __shfl_down(sq, off);
    }
    if (lane == 0){ red[wave][0]=sc; red[wave][1]=ss; red[wave][2]=sq; }
    __syncthreads();
    if (tid == 0){
      float a0=0,a1=0,a2=0;
      for (int w2=0; w2<8; ++w2){ a0+=red[w2][0]; a1+=red[w2][1]; a2+=red[w2][2]; }
      partials[work*3+0]=a0; partials[work*3+1]=a1; partials[work*3+2]=a2;
    }
  }
}

// ---------------------------------------------------------------------------
// Reduce 256 per-work partials; work<128 -> update, else reset.
__global__ __launch_bounds__(256) void k_finalize(const float* __restrict__ partials,
                                                  float* __restrict__ ubs){
  __shared__ float red[4][6];
  int tid = threadIdx.x, lane = tid & 63, wave = tid >> 6;
  float cu=0,su=0,qu=0,cr=0,sr=0,qr=0;
  {
    float c = partials[tid*3+0], s = partials[tid*3+1], q = partials[tid*3+2];
    if (tid < 128){ cu=c; su=s; qu=q; } else { cr=c; sr=s; qr=q; }
  }
#pragma unroll
  for (int off = 32; off; off >>= 1){
    cu += __shfl_down(cu, off); su += __shfl_down(su, off); qu += __shfl_down(qu, off);
    cr += __shfl_down(cr, off); sr += __shfl_down(sr, off); qr += __shfl_down(qr, off);
  }
  if (lane == 0){ red[wave][0]=cu; red[wave][1]=su; red[wave][2]=qu;
                  red[wave][3]=cr; red[wave][4]=sr; red[wave][5]=qr; }
  __syncthreads();
  if (tid < 2){
    double C=0, S=0, Q=0;
    for (int w2=0; w2<4; ++w2){
      C += red[w2][tid*3+0]; S += red[w2][tid*3+1]; Q += red[w2][tid*3+2];
    }
    float ub = 1.f;
    if (C >= 2.0){
      double mean = S / C;
      double var = (Q - C*mean*mean) / (C - 1.0);
      if (var < 0.0) var = 0.0;
      ub = (float)(mean + 3.0*sqrt(var));
    }
    ubs[tid] = ub;
    ubs[2+tid] = 1.f/ub;
  }
}

// stacked2[...,256:512] = bf16(in_state * min(reset,ub_r)/ub_r)
__global__ __launch_bounds__(256) void k_mulreset(const u16* __restrict__ G,
    const u16* __restrict__ x2pad, const float* __restrict__ ubs,
    u16* __restrict__ stacked2){
  int tid = threadIdx.x, bh = blockIdx.x;
  int b = bh >> 6, h = bh & 63;
  int px = tid >> 2, cg = tid & 3;
  float ubr = ubs[1], inv = ubs[3];
#pragma unroll
  for (int u = 0; u < 8; ++u){
    int c = cg*64 + u*8;
    int4 gv = *(const int4*)(G + (bh*64 + px)*512 + 256 + c);
    int4 sv = *(const int4*)(x2pad + (((b*72 + h+4)*72) + (px+4))*256 + c);
    float gf[8], sf[8]; unpack8(gv, gf); unpack8(sv, sf);
    union { u16 h2[8]; int4 v; } R;
#pragma unroll
    for (int j=0;j<8;j++){
      float r = fminf(gf[j], ubr) * inv;
      R.h2[j] = f2bf(sf[j] * r);
    }
    *(int4*)(stacked2 + (((b*66 + h+1)*66) + (px+1))*512 + 256 + c) = R.v;
  }
}

// new_state = s*(1-u) + o*u, NCHW fp32 out (x2 copies), via LDS transpose.
__global__ __launch_bounds__(256) void k_final(const u16* __restrict__ G,
    const u16* __restrict__ O, const float* __restrict__ in_state,
    const float* __restrict__ ubs, float* __restrict__ dout){
  __shared__ float Q[64*65];
  __shared__ float P[64*65];
  int tid = threadIdx.x, bh = blockIdx.x;
  int b = bh >> 6, h = bh & 63;
  float ubu = ubs[0], inv = ubs[2];
  int px = tid >> 2, cs = (tid & 3)*16;
  int w = tid & 63, c4 = tid >> 6;
  for (int cb = 0; cb < 4; ++cb){
#pragma unroll
    for (int tt = 0; tt < 2; ++tt){
      int cl = cs + tt*8;
      int c = cb*64 + cl;
      int4 gv = *(const int4*)(G + (bh*64 + px)*512 + c);
      int4 ov = *(const int4*)(O + (bh*64 + px)*256 + c);
      float gf[8], of[8]; unpack8(gv, gf); unpack8(ov, of);
#pragma unroll
      for (int j=0;j<8;j++){
        float u = fminf(gf[j], ubu) * inv;
        Q[px*65 + cl + j] = u;
        P[px*65 + cl + j] = of[j]*u;
      }
    }
    __syncthreads();
    for (int i = 0; i < 16; ++i){
      int cl = i*4 + c4;
      int c = cb*64 + cl;
      int gidx = (((b*256 + c)*64) + h)*64 + w;
      float s = in_state[gidx];
      float v = s*(1.f - Q[w*65 + cl]) + P[w*65 + cl];
      dout[gidx] = v;
      dout[8388608 + gidx] = v;
    }
    __syncthreads();
  }
}

// ---------------------------------------------------------------------------
extern "C" void kernel_launch(void* const* d_in, const int* in_sizes, int n_in,
                              void* d_out, int out_size, void* d_ws, size_t ws_size,
                              hipStream_t stream){
  (void)in_sizes; (void)n_in; (void)out_size; (void)ws_size;
  const float* inputs   = (const float*)d_in[0];
  const float* in_state = (const float*)d_in[1];
  const float* w_reset  = (const float*)d_in[2];
  const float* b_reset  = (const float*)d_in[3];
  const float* w_update = (const float*)d_in[4];
  const float* b_update = (const float*)d_in[5];
  const float* w_out    = (const float*)d_in[6];
  const float* b_out    = (const float*)d_in[7];
  const float* w_offset = (const float*)d_in[8];
  const float* w_align  = (const float*)d_in[9];
  float* dout = (float*)d_out;

  char* ws = (char*)d_ws;
  size_t off = 0;
  auto alloc = [&](size_t bytes)->char*{
    char* p = ws + off; off = (off + bytes + 255) & ~(size_t)255; return p;
  };
  const size_t x2pad_b   = 8ull*72*72*256*2;
  const size_t stacked_b = 8ull*66*66*512*2;
  u16* x2pad    = (u16*)alloc(x2pad_b);
  u16* stacked  = (u16*)alloc(stacked_b);
  u16* stacked2 = (u16*)alloc(stacked_b);
  float* corr   = (float*)alloc(8ull*64*64*81*4);
  float* offs   = (float*)alloc(8ull*64*64*18*4);
  u16* G        = (u16*)alloc(8ull*64*64*512*2);
  u16* O        = (u16*)alloc(8ull*64*64*256*2);
  u16* wgate    = (u16*)alloc(512ull*4608*2);
  u16* woutb    = (u16*)alloc(256ull*4608*2);
  u16* walignb  = (u16*)alloc(256ull*2304*2);
  float* woff   = (float*)alloc(1458*4);
  float* biascat= (float*)alloc(512*4);
  float* partials=(float*)alloc(1024*3*4);
  float* ubs    = (float*)alloc(4*4);

  hipMemsetAsync(x2pad,    0, x2pad_b,   stream);
  hipMemsetAsync(stacked,  0, stacked_b, stream);
  hipMemsetAsync(stacked2, 0, stacked_b, stream);

  k_repack<<<9216, 256, 0, stream>>>(w_reset, b_reset, w_update, b_update, w_out,
                                     w_offset, w_align, wgate, woutb, walignb, woff, biascat);
  k_transform<<<512, 256, 0, stream>>>(inputs, in_state, stacked, stacked2, x2pad);
  k_corr<<<512, 256, 0, stream>>>(stacked, x2pad, corr);
  k_offset<<<1024, 256, 0, stream>>>(corr, woff, offs);
  k_deform<<<512, 256, 0, stream>>>(x2pad, offs, walignb, stacked);
  k_conv256<16, true><<<256, 512, 0, stream>>>(stacked, wgate, biascat, G, partials);
  k_finalize<<<1, 256, 0, stream>>>(partials, ubs);
  k_mulreset<<<512, 256, 0, stream>>>(G, x2pad, ubs, stacked2);
  k_conv256<8, false><<<256, 512, 0, stream>>>(stacked2, woutb, b_out, O, nullptr);
  k_final<<<512, 256, 0, stream>>>(G, O, in_state, ubs, dout);
}

// Round 4
// 636.244 us; speedup vs baseline: 1.1032x; 1.0521x over previous
//
#include <hip/hip_runtime.h>
#include <stdint.h>
#include <math.h>

typedef unsigned short u16;
typedef short bf16x8 __attribute__((ext_vector_type(8)));
typedef float f32x4 __attribute__((ext_vector_type(4)));

#define MFMA16x16x32(a,b,c) __builtin_amdgcn_mfma_f32_16x16x32_bf16((a),(b),(c),0,0,0)

typedef __attribute__((address_space(3))) void as3_void;
typedef const __attribute__((address_space(1))) void as1_void;

__device__ __forceinline__ void g2l16(const void* g, void* l){
#if __has_builtin(__builtin_amdgcn_global_load_lds)
  __builtin_amdgcn_global_load_lds((as1_void*)g, (as3_void*)l, 16, 0, 0);
#else
  *(int4*)l = *(const int4*)g;
#endif
}

__device__ __forceinline__ u16 f2bf(float f){
  uint32_t u = __builtin_bit_cast(uint32_t, f);
  u += 0x7fffu + ((u >> 16) & 1u);
  return (u16)(u >> 16);
}
__device__ __forceinline__ float bf2f(u16 h){
  uint32_t u = ((uint32_t)h) << 16;
  return __builtin_bit_cast(float, u);
}
__device__ __forceinline__ void unpack8(int4 v, float* o){
  uint32_t w0=(uint32_t)v.x, w1=(uint32_t)v.y, w2=(uint32_t)v.z, w3=(uint32_t)v.w;
  o[0]=__builtin_bit_cast(float, w0<<16); o[1]=__builtin_bit_cast(float, w0&0xffff0000u);
  o[2]=__builtin_bit_cast(float, w1<<16); o[3]=__builtin_bit_cast(float, w1&0xffff0000u);
  o[4]=__builtin_bit_cast(float, w2<<16); o[5]=__builtin_bit_cast(float, w2&0xffff0000u);
  o[6]=__builtin_bit_cast(float, w3<<16); o[7]=__builtin_bit_cast(float, w3&0xffff0000u);
}
__device__ __forceinline__ int iclampi(int v,int lo,int hi){ return v<lo?lo:(v>hi?hi:v); }

// ---------------------------------------------------------------------------
// Weights frag-packed per K-tile-64 chunk (identical layout to round 3).
__global__ void k_repack(const float* __restrict__ w_reset, const float* __restrict__ b_reset,
                         const float* __restrict__ w_update, const float* __restrict__ b_update,
                         const float* __restrict__ w_out, const float* __restrict__ w_offset,
                         const float* __restrict__ w_align,
                         u16* __restrict__ wgate, u16* __restrict__ wout,
                         u16* __restrict__ walign, float* __restrict__ woff,
                         float* __restrict__ biascat){
  int idx = blockIdx.x * 256 + threadIdx.x;
  if (idx < 512*4608){           // gate: BN=256, nb in {0,1}
    int e = idx & 7, j = (idx >> 3) & 2047, chunk = idx >> 14;
    int nb = chunk & 1, kk = chunk >> 1;
    int l = j & 15, q = (j >> 4) & 3, t16 = (j >> 6) & 15, ks2 = j >> 10;
    int n = nb*256 + t16*16 + l;
    int tap = kk >> 3, ksin = kk & 7;
    int c = ksin*64 + ks2*32 + q*8 + e;
    int ky = tap/3, kx = tap%3;
    float v = (n < 256) ? w_update[((n*512 + c)*3 + ky)*3 + kx]
                        : w_reset[(((n-256)*512 + c)*3 + ky)*3 + kx];
    wgate[idx] = f2bf(v);
  }
  if (idx < 256*4608){           // out: BN=128, nb in {0,1}
    int e = idx & 7, j = (idx >> 3) & 1023, chunk = idx >> 13;
    int nb = chunk & 1, kk = chunk >> 1;
    int l = j & 15, q = (j >> 4) & 3, t8 = (j >> 6) & 7, ks2 = j >> 9;
    int n = nb*128 + t8*16 + l;
    int tap = kk >> 3, ksin = kk & 7;
    int c = ksin*64 + ks2*32 + q*8 + e;
    int ky = tap/3, kx = tap%3;
    wout[idx] = f2bf(w_out[((n*512 + c)*3 + ky)*3 + kx]);
  }
  if (idx < 256*2304){           // align (k_deform reads directly)
    int n = idx / 2304, k = idx % 2304;
    int tap = k >> 8, c = k & 255;
    int ky = tap/3, kx = tap%3;
    walign[idx] = f2bf(w_align[((n*256 + c)*3 + ky)*3 + kx]);
  }
  if (idx < 1458) woff[idx] = w_offset[idx] * (1.f/256.f);
  if (idx < 512) biascat[idx] = (idx < 256) ? b_update[idx] : b_reset[idx-256];
}

// ---------------------------------------------------------------------------
// NCHW fp32 -> NHWC bf16.
__global__ __launch_bounds__(256) void k_transform(const float* __restrict__ inputs,
    const float* __restrict__ in_state, u16* __restrict__ stacked,
    u16* __restrict__ stacked2, u16* __restrict__ x2pad){
  __shared__ u16 t1[64*264];
  __shared__ u16 t2[64*264];
  int tid = threadIdx.x, bh = blockIdx.x;
  int b = bh >> 6, h = bh & 63;
  int w = tid & 63, cq = tid >> 6;
  for (int i = 0; i < 64; ++i){
    int c = i*4 + cq;
    int gi = ((b*256 + c)*64 + h)*64 + w;
    t1[w*264 + c] = f2bf(inputs[gi]);
    t2[w*264 + c] = f2bf(in_state[gi]);
  }
  __syncthreads();
  int px = tid >> 2, cg = tid & 3;
#pragma unroll
  for (int u = 0; u < 8; ++u){
    int c = cg*64 + u*8;
    int4 v1 = *(const int4*)(t1 + px*264 + c);
    int4 v2 = *(const int4*)(t2 + px*264 + c);
    *(int4*)(stacked  + (((b*66 + h+1)*66) + (px+1))*512 + c) = v1;
    *(int4*)(stacked2 + (((b*66 + h+1)*66) + (px+1))*512 + c) = v1;
    *(int4*)(x2pad    + (((b*72 + h+4)*72) + (px+4))*256 + c) = v2;
  }
}

// ---------------------------------------------------------------------------
// Correlation as masked local GEMM.
__global__ __launch_bounds__(256) void k_corr(const u16* __restrict__ stacked,
    const u16* __restrict__ x2pad, float* __restrict__ corr){
  __shared__ u16 lA[8192];
  __shared__ u16 lB[32768];
  int tid = threadIdx.x, idx = blockIdx.x;
  int b = idx >> 6, ty = (idx >> 3) & 7, tx = idx & 7;
  int h0 = ty*8, w0 = tx*8;
  int wave = tid >> 6, lane = tid & 63, l15 = lane & 15, quad = lane >> 4;
  f32x4 acc[4][4];
#pragma unroll
  for (int i=0;i<4;i++)
#pragma unroll
    for (int j=0;j<4;j++){ f32x4 z = {0.f,0.f,0.f,0.f}; acc[i][j] = z; }

  for (int s = 0; s < 2; ++s){
#pragma unroll
    for (int i = 0; i < 4; ++i){
      int j = tid + i*256;
      int ml = j & 15, q = (j>>4)&3, mt = (j>>6)&3, ks = j >> 8;
      int px = mt*16 + ml, py = px >> 3, pxx = px & 7;
      const u16* g = stacked + (((b*66 + h0+py+1)*66) + (w0+pxx+1))*512 + s*128 + ks*32 + q*8;
      g2l16(g, lA + j*8);
    }
#pragma unroll
    for (int i = 0; i < 16; ++i){
      int j = tid + i*256;
      int nl = j & 15, q = (j>>4)&3, nt = (j>>6)&15, ks = j >> 10;
      int qp = nt*16 + nl, qy = qp >> 4, qx = qp & 15;
      const u16* g = x2pad + (((b*72 + h0+qy)*72) + (w0+qx))*256 + s*128 + ks*32 + q*8;
      g2l16(g, lB + j*8);
    }
    __syncthreads();
#pragma unroll
    for (int ks = 0; ks < 4; ++ks){
      bf16x8 bv[4];
#pragma unroll
      for (int ni=0; ni<4; ++ni){
        int nt = wave*4 + ni;
        bv[ni] = *(const bf16x8*)(lB + (((ks*16 + nt)*4 + quad)*16 + l15)*8);
      }
#pragma unroll
      for (int mi=0; mi<4; ++mi){
        bf16x8 av = *(const bf16x8*)(lA + (((ks*4 + mi)*4 + quad)*16 + l15)*8);
#pragma unroll
        for (int ni=0; ni<4; ++ni) acc[mi][ni] = MFMA16x16x32(av, bv[ni], acc[mi][ni]);
      }
    }
    __syncthreads();
  }
#pragma unroll
  for (int mi=0; mi<4; ++mi){
#pragma unroll
    for (int ni=0; ni<4; ++ni){
      int n = wave*64 + ni*16 + l15;
      int qy = n >> 4, qx = n & 15;
#pragma unroll
      for (int r=0; r<4; ++r){
        int m = mi*16 + quad*4 + r;
        int py = m >> 3, pxx = m & 7;
        int dy = qy - py, dx = qx - pxx;
        if ((unsigned)dy <= 8u && (unsigned)dx <= 8u)
          corr[(((b*64 + h0+py)*64) + (w0+pxx))*81 + dy*9 + dx] = acc[mi][ni][r];
      }
    }
  }
}

// ---------------------------------------------------------------------------
__global__ __launch_bounds__(256) void k_offset(const float* __restrict__ corr,
    const float* __restrict__ woff, float* __restrict__ offs){
  __shared__ float lc[32*84];
  __shared__ float lw[18*84];
  int tid = threadIdx.x, blk = blockIdx.x;
  int row = blk >> 1, half = blk & 1;
  int base = row*5184 + half*32*81;
  for (int i = tid; i < 32*81; i += 256){
    int px = i / 81, d = i % 81;
    lc[px*84 + d] = corr[base + i];
  }
  for (int i = tid; i < 18*84; i += 256){
    int o = i / 84, d = i % 84;
    if (d < 81) lw[i] = woff[o*81 + d];
  }
  __syncthreads();
  int px = tid & 31, og = tid >> 5;
  for (int o = og; o < 18; o += 8){
    float s = 0.f;
#pragma unroll
    for (int dd = 0; dd < 20; ++dd){
      float4 a = *(const float4*)(lc + px*84 + dd*4);
      float4 wv = *(const float4*)(lw + o*84 + dd*4);
      s += a.x*wv.x + a.y*wv.y + a.z*wv.z + a.w*wv.w;
    }
    s += lc[px*84 + 80] * lw[o*84 + 80];
    offs[(row*64 + half*32 + px)*18 + o] = s;
  }
}

// ---------------------------------------------------------------------------
// Deformable conv (unchanged).
__global__ __launch_bounds__(256) void k_deform(const u16* __restrict__ x2pad,
    const float* __restrict__ offs, const u16* __restrict__ walign,
    u16* __restrict__ stacked){
  __shared__ u16 lA[16384];
  int tid = threadIdx.x, bh = blockIdx.x;
  int b = bh >> 6, h = bh & 63;
  int wave = tid >> 6, lane = tid & 63, l15 = lane & 15, quad = lane >> 4;
  int px = tid >> 2, cg = tid & 3;
  int mt_s = px >> 4, ml_s = px & 15;
  f32x4 acc[4][4];
#pragma unroll
  for (int i=0;i<4;i++)
#pragma unroll
    for (int j=0;j<4;j++){ f32x4 z = {0.f,0.f,0.f,0.f}; acc[i][j] = z; }

  for (int tap = 0; tap < 9; ++tap){
    int ky = tap/3, kx = tap%3;
    float offy = offs[(bh*64 + px)*18 + 2*tap];
    float offx = offs[(bh*64 + px)*18 + 2*tap + 1];
    float y = (float)(h + ky - 1) + offy;
    float x = (float)(px + kx - 1) + offx;
    float y0f = floorf(y), x0f = floorf(x);
    float wy1 = y - y0f, wx1 = x - x0f;
    float wy0 = 1.f - wy1, wx0 = 1.f - wx1;
    int iy0 = iclampi((int)y0f, -4, 67), ix0 = iclampi((int)x0f, -4, 67);
    int iy1 = iclampi((int)y0f + 1, -4, 67), ix1 = iclampi((int)x0f + 1, -4, 67);
    const u16* p00 = x2pad + (((b*72 + iy0+4)*72) + (ix0+4))*256 + cg*64;
    const u16* p01 = x2pad + (((b*72 + iy0+4)*72) + (ix1+4))*256 + cg*64;
    const u16* p10 = x2pad + (((b*72 + iy1+4)*72) + (ix0+4))*256 + cg*64;
    const u16* p11 = x2pad + (((b*72 + iy1+4)*72) + (ix1+4))*256 + cg*64;
    float w00 = wy0*wx0, w01 = wy0*wx1, w10 = wy1*wx0, w11 = wy1*wx1;
#pragma unroll
    for (int u = 0; u < 8; ++u){
      int4 v00 = *(const int4*)(p00 + u*8);
      int4 v01 = *(const int4*)(p01 + u*8);
      int4 v10 = *(const int4*)(p10 + u*8);
      int4 v11 = *(const int4*)(p11 + u*8);
      float a00[8], a01[8], a10[8], a11[8];
      unpack8(v00,a00); unpack8(v01,a01); unpack8(v10,a10); unpack8(v11,a11);
      union { u16 h2[8]; int4 v; } R;
#pragma unroll
      for (int jj = 0; jj < 8; ++jj)
        R.h2[jj] = f2bf(w00*a00[jj] + w01*a01[jj] + w10*a10[jj] + w11*a11[jj]);
      int ch = cg*64 + u*8;
      int ks = ch >> 5, q = (ch >> 3) & 3;
      *(int4*)(lA + (((ks*4 + mt_s)*4 + q)*16 + ml_s)*8) = R.v;
    }
    __syncthreads();
#pragma unroll
    for (int ks = 0; ks < 8; ++ks){
      bf16x8 bv[4];
#pragma unroll
      for (int ni=0; ni<4; ++ni){
        int n = wave*64 + ni*16 + l15;
        bv[ni] = *(const bf16x8*)(walign + n*2304 + tap*256 + ks*32 + quad*8);
      }
#pragma unroll
      for (int mi=0; mi<4; ++mi){
        bf16x8 av = *(const bf16x8*)(lA + (((ks*4 + mi)*4 + quad)*16 + l15)*8);
#pragma unroll
        for (int ni=0; ni<4; ++ni) acc[mi][ni] = MFMA16x16x32(av, bv[ni], acc[mi][ni]);
      }
    }
    __syncthreads();
  }
#pragma unroll
  for (int mi=0; mi<4; ++mi){
#pragma unroll
    for (int ni=0; ni<4; ++ni){
      int n = wave*64 + ni*16 + l15;
#pragma unroll
      for (int r=0; r<4; ++r){
        int m = mi*16 + quad*4 + r;
        stacked[(((b*66 + h+1)*66) + (m+1))*512 + 256 + n] = f2bf(acc[mi][ni][r]);
      }
    }
  }
}

// ---------------------------------------------------------------------------
// Staging: split by ks2 (K-half). Slot j = const | tid -> LDS dest is
// wave-uniform base + lane*16 (global_load_lds requirement).
__device__ __forceinline__ void stageA_k(u16* __restrict__ dst,
    const u16* __restrict__ in, int b, int h0, int kk, int ks2, int tid){
  int tap = kk >> 3, ksin = kk & 7;
  int ky = tap/3, kx = tap - ky*3;
  const u16* abase = in + ((b*66 + h0 + ky)*66 + kx)*512 + ksin*64 + ks2*32;
#pragma unroll
  for (int i = 0; i < 2; ++i){
    int j = (ks2<<10) | (i<<9) | tid;
    int l = j & 15, q = (j >> 4) & 3, t16 = (j >> 6) & 15;
    int px = t16*16 + l, r = px >> 6, w = px & 63;
    g2l16(abase + (r*66 + w)*512 + q*8, dst + j*8);
  }
}
__device__ __forceinline__ void stageB16_k(u16* __restrict__ dst,
    const u16* __restrict__ wts, int nb, int kk, int ks2, int tid){
  const u16* wch = wts + (size_t)(kk*2 + nb) * 16384;
#pragma unroll
  for (int i = 0; i < 2; ++i){
    int j = (ks2<<10) | (i<<9) | tid;
    g2l16(wch + j*8, dst + j*8);
  }
}
__device__ __forceinline__ void stageB8_k(u16* __restrict__ dst,
    const u16* __restrict__ wts, int nb, int kk, int ks2, int tid){
  const u16* wch = wts + (size_t)(kk*2 + nb) * 8192;
  int j = (ks2<<9) | tid;
  g2l16(wch + j*8, dst + j*8);
}

// ---------------------------------------------------------------------------
// Pipelined phase (NT=16): issue ds_reads for the NEXT phase's operands into
// the alternate register set (compiler inserts a counted lgkm wait before the
// MFMAs, which consume registers loaded one phase earlier), issue staging,
// MFMA, then (optionally) counted-vmcnt + barrier. 3 barriers / K-tile.
#define PH16(CMH, AVC, BVC, AVN, BVN, LOADB, RA, RB, NMH, NK2, STG, EPI) do { \
  _Pragma("unroll") \
  for (int m4_=0;m4_<4;++m4_) \
    AVN[m4_] = *(const bf16x8*)((const u16*)(RA) + ((((NK2)*16 + wm*8 + (NMH)*4 + m4_)*4 + quad)*16 + l15)*8); \
  if (LOADB){ \
    _Pragma("unroll") \
    for (int ni_=0;ni_<4;++ni_) \
      BVN[ni_] = *(const bf16x8*)((const u16*)(RB) + ((((NK2)*16 + wn*4 + ni_)*4 + quad)*16 + l15)*8); \
  } \
  STG; \
  __builtin_amdgcn_sched_barrier(0); \
  __builtin_amdgcn_s_setprio(1); \
  _Pragma("unroll") \
  for (int m4_=0;m4_<4;++m4_){ \
    _Pragma("unroll") \
    for (int ni_=0;ni_<4;++ni_) \
      acc[(CMH)*4+m4_][ni_] = MFMA16x16x32(AVC[m4_], BVC[ni_], acc[(CMH)*4+m4_][ni_]); \
  } \
  __builtin_amdgcn_s_setprio(0); \
  __builtin_amdgcn_sched_barrier(0); \
  EPI; \
} while(0)

// Pipelined phase (NT=8): 2 phases/K-tile, one K-half each, 16 MFMA/phase.
#define PH8(AVC, BVC, AVN, BVN, RA, RB, NK2, STG, EPI) do { \
  _Pragma("unroll") \
  for (int m8_=0;m8_<8;++m8_) \
    AVN[m8_] = *(const bf16x8*)((const u16*)(RA) + ((((NK2)*16 + wm*8 + m8_)*4 + quad)*16 + l15)*8); \
  _Pragma("unroll") \
  for (int ni_=0;ni_<2;++ni_) \
    BVN[ni_] = *(const bf16x8*)((const u16*)(RB) + ((((NK2)*8 + wn*2 + ni_)*4 + quad)*16 + l15)*8); \
  STG; \
  __builtin_amdgcn_sched_barrier(0); \
  __builtin_amdgcn_s_setprio(1); \
  _Pragma("unroll") \
  for (int m8_=0;m8_<8;++m8_){ \
    _Pragma("unroll") \
    for (int ni_=0;ni_<2;++ni_) \
      acc[m8_][ni_] = MFMA16x16x32(AVC[m8_], BVC[ni_], acc[m8_][ni_]); \
  } \
  __builtin_amdgcn_s_setprio(0); \
  __builtin_amdgcn_sched_barrier(0); \
  EPI; \
} while(0)

#define VMBAR(N) do { \
  if (N) { asm volatile("s_waitcnt vmcnt(" #N ")" ::: "memory"); } \
  else   { asm volatile("s_waitcnt vmcnt(0)" ::: "memory"); } \
  asm volatile("" ::: "memory"); \
  __builtin_amdgcn_s_barrier(); \
} while(0)
#define BARONLY do { asm volatile("" ::: "memory"); __builtin_amdgcn_s_barrier(); } while(0)

// 3x3 conv, implicit GEMM, 256px x (NT*16)n tile, 8 waves (2M x 4N), BK=64.
// One-phase register lookahead: LDS-read drain overlaps the previous phase's
// MFMA cluster. Counted vmcnt (2-phase prefetch distance); minimal barriers.
template<int NT, bool STATS>
__global__ __launch_bounds__(512, 2) void k_conv256(const u16* __restrict__ in,
    const u16* __restrict__ wts, const float* __restrict__ bias,
    u16* __restrict__ outp, float* __restrict__ partials){
  constexpr int NI = NT / 4;
  __shared__ u16 lA[2][16384];      // 256 px x 64 ch per buffer
  __shared__ u16 lB[2][NT*1024];    // (NT*16) n x 64 ch per buffer

  int tid = threadIdx.x, g = blockIdx.x;
  int work = (g & 7) * 32 + (g >> 3);     // bijective XCD swizzle (256 % 8 == 0)
  int nb = work >> 7, mt = work & 127;    // nb-major: 32 works/XCD share B panel
  int b = mt >> 4, h0 = (mt & 15) * 4;
  int wave = tid >> 6, lane = tid & 63, l15 = lane & 15, quad = lane >> 4;
  int wm = wave & 1, wn = wave >> 1;

  f32x4 acc[8][NI];
#pragma unroll
  for (int i=0;i<8;i++)
#pragma unroll
    for (int j=0;j<NI;j++){ f32x4 z = {0.f,0.f,0.f,0.f}; acc[i][j] = z; }

  if constexpr (NT == 16){
    bf16x8 avA[4], avB[4], bvA[4], bvB[4];
    // Prologue: stage tile 0 (G01 = {gA0,gB0}, G23 = {gA1,gB1}); retire G01;
    // globalize; issue phase-0 operand reads.
    stageA_k(&lA[0][0], in, b, h0, 0, 0, tid);
    stageB16_k(&lB[0][0], wts, nb, 0, 0, tid);
    stageA_k(&lA[0][0], in, b, h0, 0, 1, tid);
    stageB16_k(&lB[0][0], wts, nb, 0, 1, tid);
    asm volatile("s_waitcnt vmcnt(4)" ::: "memory");
    asm volatile("" ::: "memory");
    __builtin_amdgcn_s_barrier();
#pragma unroll
    for (int m4_=0;m4_<4;++m4_)
      avA[m4_] = *(const bf16x8*)(&lA[0][0] + (((wm*8 + m4_)*4 + quad)*16 + l15)*8);
#pragma unroll
    for (int ni_=0;ni_<4;++ni_)
      bvA[ni_] = *(const bf16x8*)(&lB[0][0] + (((wn*4 + ni_)*4 + quad)*16 + l15)*8);

#pragma unroll 1
    for (int t = 0; t < 72; ++t){
      int d = t & 1;
      const u16* Acur = &lA[d][0];
      const u16* Bcur = &lB[d][0];
      u16* Anx = &lA[d^1][0];
      u16* Bnx = &lB[d^1][0];
      bool hn = (t < 71);
      int kn = t + 1;
      // p0: MFMA(avA,bvA)->(mh0,k0); rd avB=(mh1,k0)@cur; stage G01(t+1); vm+bar
      PH16(0, avA, bvA, avB, bvB, 0, Acur, Bcur, 1, 0,
           if (hn){ stageA_k(Anx, in, b, h0, kn, 0, tid);
                    stageB16_k(Bnx, wts, nb, kn, 0, tid); },
           if (hn) VMBAR(4); else VMBAR(0));
      // p1: MFMA(avB,bvA)->(mh1,k0); rd avA=(mh0,k1)@cur + bvB=(k1)@cur
      PH16(1, avB, bvA, avA, bvB, 1, Acur, Bcur, 0, 1, , );
      // p2: MFMA(avA,bvB)->(mh0,k1); rd avB=(mh1,k1)@cur; stage G23(t+1); vm+bar
      PH16(0, avA, bvB, avB, bvA, 0, Acur, Bcur, 1, 1,
           if (hn){ stageA_k(Anx, in, b, h0, kn, 1, tid);
                    stageB16_k(Bnx, wts, nb, kn, 1, tid); },
           if (hn) VMBAR(4); else VMBAR(0));
      // p3: MFMA(avB,bvB)->(mh1,k1); rd avA=(mh0,k0)@nx + bvA=(k0)@nx; bar
      PH16(1, avB, bvB, avA, bvA, 1, Anx, Bnx, 0, 0, , BARONLY);
    }
  } else {
    bf16x8 avA[8], avB[8], bvA[2], bvB[2];
    // Prologue: stage K0(0), K1(0), K0(1); retire K0(0),K1(0); globalize;
    // issue phase-0 operand reads (k0 of tile 0).
    stageA_k(&lA[0][0], in, b, h0, 0, 0, tid);
    stageB8_k(&lB[0][0], wts, nb, 0, 0, tid);
    stageA_k(&lA[0][0], in, b, h0, 0, 1, tid);
    stageB8_k(&lB[0][0], wts, nb, 0, 1, tid);
    stageA_k(&lA[1][0], in, b, h0, 1, 0, tid);
    stageB8_k(&lB[1][0], wts, nb, 1, 0, tid);
    asm volatile("s_waitcnt vmcnt(3)" ::: "memory");
    asm volatile("" ::: "memory");
    __builtin_amdgcn_s_barrier();
#pragma unroll
    for (int m8_=0;m8_<8;++m8_)
      avA[m8_] = *(const bf16x8*)(&lA[0][0] + (((wm*8 + m8_)*4 + quad)*16 + l15)*8);
#pragma unroll
    for (int ni_=0;ni_<2;++ni_)
      bvA[ni_] = *(const bf16x8*)(&lB[0][0] + (((wn*2 + ni_)*4 + quad)*16 + l15)*8);

#pragma unroll 1
    for (int t = 0; t < 72; ++t){
      int d = t & 1;
      const u16* Acur = &lA[d][0];
      const u16* Bcur = &lB[d][0];
      u16* Anx = &lA[d^1][0];
      u16* Bnx = &lB[d^1][0];
      u16* Acu = &lA[d][0];           // staging target for K0(t+2) (same parity)
      u16* Bcu = &lB[d][0];
      bool h1 = (t < 71), h2 = (t < 70);
      int kn = t + 1;
      // p0: MFMA(avA,bvA)->k0; rd avB,bvB=(k1)@cur; stage K1(t+1)->nx; vm+bar
      PH8(avA, bvA, avB, bvB, Acur, Bcur, 1,
          if (h1){ stageA_k(Anx, in, b, h0, kn, 1, tid);
                   stageB8_k(Bnx, wts, nb, kn, 1, tid); },
          if (h1) VMBAR(3); else VMBAR(0));
      // p1: MFMA(avB,bvB)->k1; rd avA,bvA=(k0)(t+1)@nx; stage K0(t+2)->cur; vm+bar
      PH8(avB, bvB, avA, bvA, Anx, Bnx, 0,
          if (h2){ stageA_k(Acu, in, b, h0, t+2, 0, tid);
                   stageB8_k(Bcu, wts, nb, t+2, 0, tid); },
          if (h2) VMBAR(3); else VMBAR(0));
    }
  }

  float bvl[NI];
#pragma unroll
  for (int ni = 0; ni < NI; ++ni)
    bvl[ni] = bias[nb*(NT*16) + wn*(NI*16) + ni*16 + l15];
  float sc = 0.f, ss = 0.f, sq = 0.f;
#pragma unroll
  for (int mi=0; mi<8; ++mi){
#pragma unroll
    for (int ni=0; ni<NI; ++ni){
      int n = nb*(NT*16) + wn*(NI*16) + ni*16 + l15;
#pragma unroll
      for (int r=0; r<4; ++r){
        int m = wm*128 + mi*16 + quad*4 + r;
        int row = h0 + (m >> 6), w = m & 63;
        float v = acc[mi][ni][r] + bvl[ni];
        v = fmaxf(v, 0.f);
        outp[(((b*64 + row)*64) + w)*(NT*32) + n] = f2bf(v);
        if (STATS){ sc += (v > 0.f) ? 1.f : 0.f; ss += v; sq += v*v; }
      }
    }
  }
  if constexpr (STATS){
    __shared__ float red[8][3];
#pragma unroll
    for (int off = 32; off; off >>= 1){
      sc += __shfl_down(sc, off); ss += __shfl_down(ss, off); sq += __shfl_down(sq, off);
    }
    if (lane == 0){ red[wave][0]=sc; red[wave][1]=ss; red[wave][2]=sq; }
    __syncthreads();
    if (tid == 0){
      float a0=0,a1=0,a2=0;
      for (int w2=0; w2<8; ++w2){ a0+=red[w2][0]; a1+=red[w2][1]; a2+=red[w2][2]; }
      partials[work*3+0]=a0; partials[work*3+1]=a1; partials[work*3+2]=a2;
    }
  }
}

// ---------------------------------------------------------------------------
// Reduce 256 per-work partials; work<128 -> update, else reset.
__global__ __launch_bounds__(256) void k_finalize(const float* __restrict__ partials,
                                                  float* __restrict__ ubs){
  __shared__ float red[4][6];
  int tid = threadIdx.x, lane = tid & 63, wave = tid >> 6;
  float cu=0,su=0,qu=0,cr=0,sr=0,qr=0;
  {
    float c = partials[tid*3+0], s = partials[tid*3+1], q = partials[tid*3+2];
    if (tid < 128){ cu=c; su=s; qu=q; } else { cr=c; sr=s; qr=q; }
  }
#pragma unroll
  for (int off = 32; off; off >>= 1){
    cu += __shfl_down(cu, off); su += __shfl_down(su, off); qu += __shfl_down(qu, off);
    cr += __shfl_down(cr, off); sr += __shfl_down(sr, off); qr += __shfl_down(qr, off);
  }
  if (lane == 0){ red[wave][0]=cu; red[wave][1]=su; red[wave][2]=qu;
                  red[wave][3]=cr; red[wave][4]=sr; red[wave][5]=qr; }
  __syncthreads();
  if (tid < 2){
    double C=0, S=0, Q=0;
    for (int w2=0; w2<4; ++w2){
      C += red[w2][tid*3+0]; S += red[w2][tid*3+1]; Q += red[w2][tid*3+2];
    }
    float ub = 1.f;
    if (C >= 2.0){
      double mean = S / C;
      double var = (Q - C*mean*mean) / (C - 1.0);
      if (var < 0.0) var = 0.0;
      ub = (float)(mean + 3.0*sqrt(var));
    }
    ubs[tid] = ub;
    ubs[2+tid] = 1.f/ub;
  }
}

// stacked2[...,256:512] = bf16(in_state * min(reset,ub_r)/ub_r)
__global__ __launch_bounds__(256) void k_mulreset(const u16* __restrict__ G,
    const u16* __restrict__ x2pad, const float* __restrict__ ubs,
    u16* __restrict__ stacked2){
  int tid = threadIdx.x, bh = blockIdx.x;
  int b = bh >> 6, h = bh & 63;
  int px = tid >> 2, cg = tid & 3;
  float ubr = ubs[1], inv = ubs[3];
#pragma unroll
  for (int u = 0; u < 8; ++u){
    int c = cg*64 + u*8;
    int4 gv = *(const int4*)(G + (bh*64 + px)*512 + 256 + c);
    int4 sv = *(const int4*)(x2pad + (((b*72 + h+4)*72) + (px+4))*256 + c);
    float gf[8], sf[8]; unpack8(gv, gf); unpack8(sv, sf);
    union { u16 h2[8]; int4 v; } R;
#pragma unroll
    for (int j=0;j<8;j++){
      float r = fminf(gf[j], ubr) * inv;
      R.h2[j] = f2bf(sf[j] * r);
    }
    *(int4*)(stacked2 + (((b*66 + h+1)*66) + (px+1))*512 + 256 + c) = R.v;
  }
}

// new_state = s*(1-u) + o*u, NCHW fp32 out (x2 copies), via LDS transpose.
__global__ __launch_bounds__(256) void k_final(const u16* __restrict__ G,
    const u16* __restrict__ O, const float* __restrict__ in_state,
    const float* __restrict__ ubs, float* __restrict__ dout){
  __shared__ float Q[64*65];
  __shared__ float P[64*65];
  int tid = threadIdx.x, bh = blockIdx.x;
  int b = bh >> 6, h = bh & 63;
  float ubu = ubs[0], inv = ubs[2];
  int px = tid >> 2, cs = (tid & 3)*16;
  int w = tid & 63, c4 = tid >> 6;
  for (int cb = 0; cb < 4; ++cb){
#pragma unroll
    for (int tt = 0; tt < 2; ++tt){
      int cl = cs + tt*8;
      int c = cb*64 + cl;
      int4 gv = *(const int4*)(G + (bh*64 + px)*512 + c);
      int4 ov = *(const int4*)(O + (bh*64 + px)*256 + c);
      float gf[8], of[8]; unpack8(gv, gf); unpack8(ov, of);
#pragma unroll
      for (int j=0;j<8;j++){
        float u = fminf(gf[j], ubu) * inv;
        Q[px*65 + cl + j] = u;
        P[px*65 + cl + j] = of[j]*u;
      }
    }
    __syncthreads();
    for (int i = 0; i < 16; ++i){
      int cl = i*4 + c4;
      int c = cb*64 + cl;
      int gidx = (((b*256 + c)*64) + h)*64 + w;
      float s = in_state[gidx];
      float v = s*(1.f - Q[w*65 + cl]) + P[w*65 + cl];
      dout[gidx] = v;
      dout[8388608 + gidx] = v;
    }
    __syncthreads();
  }
}

// ---------------------------------------------------------------------------
extern "C" void kernel_launch(void* const* d_in, const int* in_sizes, int n_in,
                              void* d_out, int out_size, void* d_ws, size_t ws_size,
                              hipStream_t stream){
  (void)in_sizes; (void)n_in; (void)out_size; (void)ws_size;
  const float* inputs   = (const float*)d_in[0];
  const float* in_state = (const float*)d_in[1];
  const float* w_reset  = (const float*)d_in[2];
  const float* b_reset  = (const float*)d_in[3];
  const float* w_update = (const float*)d_in[4];
  const float* b_update = (const float*)d_in[5];
  const float* w_out    = (const float*)d_in[6];
  const float* b_out    = (const float*)d_in[7];
  const float* w_offset = (const float*)d_in[8];
  const float* w_align  = (const float*)d_in[9];
  float* dout = (float*)d_out;

  char* ws = (char*)d_ws;
  size_t off = 0;
  auto alloc = [&](size_t bytes)->char*{
    char* p = ws + off; off = (off + bytes + 255) & ~(size_t)255; return p;
  };
  const size_t x2pad_b   = 8ull*72*72*256*2;
  const size_t stacked_b = 8ull*66*66*512*2;
  u16* x2pad    = (u16*)alloc(x2pad_b);
  u16* stacked  = (u16*)alloc(stacked_b);
  u16* stacked2 = (u16*)alloc(stacked_b);
  float* corr   = (float*)alloc(8ull*64*64*81*4);
  float* offs   = (float*)alloc(8ull*64*64*18*4);
  u16* G        = (u16*)alloc(8ull*64*64*512*2);
  u16* O        = (u16*)alloc(8ull*64*64*256*2);
  u16* wgate    = (u16*)alloc(512ull*4608*2);
  u16* woutb    = (u16*)alloc(256ull*4608*2);
  u16* walignb  = (u16*)alloc(256ull*2304*2);
  float* woff   = (float*)alloc(1458*4);
  float* biascat= (float*)alloc(512*4);
  float* partials=(float*)alloc(1024*3*4);
  float* ubs    = (float*)alloc(4*4);

  hipMemsetAsync(x2pad,    0, x2pad_b,   stream);
  hipMemsetAsync(stacked,  0, stacked_b, stream);
  hipMemsetAsync(stacked2, 0, stacked_b, stream);

  k_repack<<<9216, 256, 0, stream>>>(w_reset, b_reset, w_update, b_update, w_out,
                                     w_offset, w_align, wgate, woutb, walignb, woff, biascat);
  k_transform<<<512, 256, 0, stream>>>(inputs, in_state, stacked, stacked2, x2pad);
  k_corr<<<512, 256, 0, stream>>>(stacked, x2pad, corr);
  k_offset<<<1024, 256, 0, stream>>>(corr, woff, offs);
  k_deform<<<512, 256, 0, stream>>>(x2pad, offs, walignb, stacked);
  k_conv256<16, true><<<256, 512, 0, stream>>>(stacked, wgate, biascat, G, partials);
  k_finalize<<<1, 256, 0, stream>>>(partials, ubs);
  k_mulreset<<<512, 256, 0, stream>>>(G, x2pad, ubs, stacked2);
  k_conv256<8, false><<<256, 512, 0, stream>>>(stacked2, woutb, b_out, O, nullptr);
  k_final<<<512, 256, 0, stream>>>(G, O, in_state, ubs, dout);
}